// Round 1
// baseline (520.966 us; speedup 1.0000x reference)
//
#include <hip/hip_runtime.h>

// CrossAttention: B=4, SQ=SKV=2048, DQ=DKV=1024, H=1024, NH=16, HD=64
// Pipeline (all bf16 MFMA, fp32 accum):
//   1) Q = query @ Wq + bq   -> ws bf16 [8192][1024]
//   2) K = kv    @ Wk + bk   -> ws bf16
//   3) V = kv    @ Wv + bv   -> ws bf16
//   4) flash attention per (b,h, 64-row q tile) -> O bf16 in ws
//   5) out = O @ Wo + bo     -> d_out fp32
// Workspace use: 4 * 8192*1024*2B = 64 MB.

typedef short s16x8 __attribute__((ext_vector_type(8)));   // 8 bf16 (4 VGPR)
typedef float f32x4 __attribute__((ext_vector_type(4)));
typedef unsigned short u16;

__device__ __forceinline__ u16 f2bf(float f) {
    union { float f; unsigned u; } v; v.f = f;
    unsigned r = v.u + 0x7fffu + ((v.u >> 16) & 1u);  // RNE
    return (u16)(r >> 16);
}

// Row-major LDS tile with 128B rows, XOR-swizzled to kill the 16-way
// bank conflict on column-slice ds_read_b128 (guide §6 G4).
// colBytes must be 16B-aligned for vector ops (XOR only touches bits 4..6).
__device__ __forceinline__ int swz(int row, int colBytes) {
    return row * 128 + (colBytes ^ ((row & 7) << 4));
}

// ---------------- GEMM: C[M,N] = A[M,K] @ W[K,N] + bias ----------------
// 64x64 tile, 4 waves (2x2), each wave 32x32 via 2x2 mfma_16x16x32 frags.
template<bool A_IS_F32, bool OUT_BF16>
__global__ __launch_bounds__(256)
void gemm_bias_64(const void* __restrict__ Av, const float* __restrict__ W,
                  const float* __restrict__ bias, void* __restrict__ Cout,
                  int M, int N, int K)
{
    __shared__ __align__(16) char smem[16384];
    char* As = smem;           // bf16 [64 m][64 k] swizzled (128B rows)
    char* Ws = smem + 8192;    // bf16 Wt [64 n][64 k] swizzled

    const int tid  = threadIdx.x;
    const int lane = tid & 63, wave = tid >> 6;
    const int g = lane >> 4, ln = lane & 15;
    const int wm = wave >> 1, wn = wave & 1;
    const int bm = blockIdx.x, bn = blockIdx.y;

    f32x4 acc[2][2] = {};

    const int srow = tid >> 2;          // 0..63
    const int sch  = (tid & 3) * 16;    // element chunk within 64

    for (int k0 = 0; k0 < K; k0 += 64) {
        // ---- stage A tile [64][64] -> bf16 swizzled
        if constexpr (A_IS_F32) {
            const float* a = (const float*)Av + (size_t)(bm * 64 + srow) * K + k0 + sch;
            const f32x4* a4 = (const f32x4*)a;
            #pragma unroll
            for (int c = 0; c < 2; ++c) {
                f32x4 x = a4[c * 2 + 0], y = a4[c * 2 + 1];
                s16x8 wv;
                #pragma unroll
                for (int j = 0; j < 4; ++j) {
                    wv[j]     = (short)f2bf(x[j]);
                    wv[4 + j] = (short)f2bf(y[j]);
                }
                *(s16x8*)(As + swz(srow, sch * 2 + c * 16)) = wv;
            }
        } else {
            const u16* a = (const u16*)Av + (size_t)(bm * 64 + srow) * K + k0 + sch;
            *(s16x8*)(As + swz(srow, sch * 2 + 0))  = *(const s16x8*)(a + 0);
            *(s16x8*)(As + swz(srow, sch * 2 + 16)) = *(const s16x8*)(a + 8);
        }
        // ---- stage W tile transposed: Wt[n][k] bf16 swizzled
        {
            const float* wsrc = W + (size_t)(k0 + srow) * N + bn * 64 + sch;
            #pragma unroll
            for (int j = 0; j < 16; ++j) {
                int n = sch + j;
                *(short*)(Ws + n * 128 + ((srow * 2) ^ ((n & 7) << 4))) = (short)f2bf(wsrc[j]);
            }
        }
        __syncthreads();
        // ---- MFMA
        #pragma unroll
        for (int kk = 0; kk < 2; ++kk) {
            s16x8 af[2], bfr[2];
            #pragma unroll
            for (int mi = 0; mi < 2; ++mi)
                af[mi] = *(const s16x8*)(As + swz(wm * 32 + mi * 16 + ln, kk * 64 + g * 16));
            #pragma unroll
            for (int ni = 0; ni < 2; ++ni)
                bfr[ni] = *(const s16x8*)(Ws + swz(wn * 32 + ni * 16 + ln, kk * 64 + g * 16));
            #pragma unroll
            for (int mi = 0; mi < 2; ++mi)
                #pragma unroll
                for (int ni = 0; ni < 2; ++ni)
                    acc[mi][ni] = __builtin_amdgcn_mfma_f32_16x16x32_bf16(
                        af[mi], bfr[ni], acc[mi][ni], 0, 0, 0);
        }
        __syncthreads();
    }
    // ---- epilogue: D col = lane&15, row = 4*(lane>>4)+r
    #pragma unroll
    for (int mi = 0; mi < 2; ++mi) {
        #pragma unroll
        for (int ni = 0; ni < 2; ++ni) {
            int col = bn * 64 + wn * 32 + ni * 16 + ln;
            float bv = bias[col];
            #pragma unroll
            for (int r = 0; r < 4; ++r) {
                int row = bm * 64 + wm * 32 + mi * 16 + 4 * g + r;
                float v = acc[mi][ni][r] + bv;
                if constexpr (OUT_BF16)
                    ((u16*)Cout)[(size_t)row * N + col] = f2bf(v);
                else
                    ((float*)Cout)[(size_t)row * N + col] = v;
            }
        }
    }
}

// ---------------- Flash attention ----------------
// Block: 64 q-rows for one (b,h); 4 waves x 16 rows. KV tiles of 64.
__global__ __launch_bounds__(256)
void attn_fwd(const u16* __restrict__ Q, const u16* __restrict__ Kg,
              const u16* __restrict__ Vg, u16* __restrict__ O)
{
    __shared__ __align__(16) char smem[24576];
    char* Ks  = smem;            // K  [64 kv][64 d] bf16 swizzled
    char* Vts = smem + 8192;     // Vt [64 d][64 kv] bf16 swizzled
    char* Ps  = smem + 16384;    // P  [64 q][64 kv] bf16 swizzled

    const int tid = threadIdx.x, lane = tid & 63, wave = tid >> 6;
    const int g = lane >> 4, ln = lane & 15;
    const int qt = blockIdx.x, bh = blockIdx.y;
    const int b = bh >> 4, h = bh & 15;

    const size_t qoff  = ((size_t)(b * 2048 + qt * 64)) * 1024 + h * 64;
    const size_t kvoff = ((size_t)(b * 2048)) * 1024 + h * 64;

    // Q fragments: A row = lane&15 (wave's local q), k = d = kk*32 + 8g + j
    s16x8 aq[2];
    #pragma unroll
    for (int kk = 0; kk < 2; ++kk)
        aq[kk] = *(const s16x8*)(Q + qoff + (size_t)(wave * 16 + ln) * 1024 + kk * 32 + g * 8);

    float m_run[4], l_run[4];
    f32x4 o_acc[4] = {};
    #pragma unroll
    for (int r = 0; r < 4; ++r) { m_run[r] = -1e30f; l_run[r] = 0.0f; }

    const float sc = 0.125f * 1.44269504088896f;  // (1/sqrt(64)) * log2(e)

    const int srow = tid >> 2;        // 0..63
    const int sch  = (tid & 3) * 16;  // element chunk

    for (int kt = 0; kt < 32; ++kt) {
        const int kv0 = kt * 64;
        // stage K [kv][d]
        {
            const u16* src = Kg + kvoff + (size_t)(kv0 + srow) * 1024 + sch;
            *(s16x8*)(Ks + swz(srow, sch * 2 + 0))  = *(const s16x8*)(src + 0);
            *(s16x8*)(Ks + swz(srow, sch * 2 + 16)) = *(const s16x8*)(src + 8);
        }
        // stage V transposed -> Vt[d][kv]
        {
            const u16* src = Vg + kvoff + (size_t)(kv0 + srow) * 1024 + sch;
            s16x8 v0 = *(const s16x8*)(src + 0);
            s16x8 v1 = *(const s16x8*)(src + 8);
            #pragma unroll
            for (int j = 0; j < 8; ++j) {
                int d0 = sch + j, d1 = sch + 8 + j;
                *(short*)(Vts + d0 * 128 + ((srow * 2) ^ ((d0 & 7) << 4))) = v0[j];
                *(short*)(Vts + d1 * 128 + ((srow * 2) ^ ((d1 & 7) << 4))) = v1[j];
            }
        }
        __syncthreads();

        // S = Q K^T : frag f covers kv = f*16 + ln; rows = wave*16 + 4g + r
        f32x4 s[4] = {};
        #pragma unroll
        for (int f = 0; f < 4; ++f) {
            #pragma unroll
            for (int kk = 0; kk < 2; ++kk) {
                s16x8 bk = *(const s16x8*)(Ks + swz(f * 16 + ln, kk * 64 + g * 16));
                s[f] = __builtin_amdgcn_mfma_f32_16x16x32_bf16(aq[kk], bk, s[f], 0, 0, 0);
            }
        }
        #pragma unroll
        for (int f = 0; f < 4; ++f) s[f] *= sc;

        // online softmax over 16-lane groups (lanes of a group share 4 q-rows)
        float mt[4], rs[4], mn[4], scl[4];
        #pragma unroll
        for (int r = 0; r < 4; ++r)
            mt[r] = fmaxf(fmaxf(s[0][r], s[1][r]), fmaxf(s[2][r], s[3][r]));
        #pragma unroll
        for (int off = 1; off <= 8; off <<= 1)
            #pragma unroll
            for (int r = 0; r < 4; ++r)
                mt[r] = fmaxf(mt[r], __shfl_xor(mt[r], off, 64));
        #pragma unroll
        for (int r = 0; r < 4; ++r) {
            mn[r]  = fmaxf(m_run[r], mt[r]);
            scl[r] = exp2f(m_run[r] - mn[r]);
        }
        #pragma unroll
        for (int f = 0; f < 4; ++f)
            #pragma unroll
            for (int r = 0; r < 4; ++r)
                s[f][r] = exp2f(s[f][r] - mn[r]);
        #pragma unroll
        for (int r = 0; r < 4; ++r)
            rs[r] = (s[0][r] + s[1][r]) + (s[2][r] + s[3][r]);
        #pragma unroll
        for (int off = 1; off <= 8; off <<= 1)
            #pragma unroll
            for (int r = 0; r < 4; ++r)
                rs[r] += __shfl_xor(rs[r], off, 64);
        #pragma unroll
        for (int r = 0; r < 4; ++r) {
            l_run[r] = l_run[r] * scl[r] + rs[r];
            m_run[r] = mn[r];
        }
        #pragma unroll
        for (int f = 0; f < 4; ++f)
            #pragma unroll
            for (int r = 0; r < 4; ++r)
                o_acc[f][r] *= scl[r];

        // write P (bf16) to swizzled LDS; lane holds rows 4g+r, kv = f*16+ln
        #pragma unroll
        for (int f = 0; f < 4; ++f)
            #pragma unroll
            for (int r = 0; r < 4; ++r) {
                int lq = wave * 16 + 4 * g + r;
                int kv = f * 16 + ln;
                *(short*)(Ps + lq * 128 + ((kv * 2) ^ ((lq & 7) << 4))) = (short)f2bf(s[f][r]);
            }
        __syncthreads();

        // O += P @ V : A row = q = lane&15, k = kv; B col = d, k = kv
        #pragma unroll
        for (int ks = 0; ks < 2; ++ks) {
            s16x8 pf = *(const s16x8*)(Ps + swz(wave * 16 + ln, ks * 64 + g * 16));
            #pragma unroll
            for (int f = 0; f < 4; ++f) {
                s16x8 vf = *(const s16x8*)(Vts + swz(f * 16 + ln, ks * 64 + g * 16));
                o_acc[f] = __builtin_amdgcn_mfma_f32_16x16x32_bf16(pf, vf, o_acc[f], 0, 0, 0);
            }
        }
        __syncthreads();
    }

    // normalize + store O (bf16)
    #pragma unroll
    for (int f = 0; f < 4; ++f) {
        #pragma unroll
        for (int r = 0; r < 4; ++r) {
            int lq = wave * 16 + 4 * g + r;
            int d  = f * 16 + ln;
            float v = o_acc[f][r] * (1.0f / l_run[r]);
            O[qoff + (size_t)lq * 1024 + d] = f2bf(v);
        }
    }
}

extern "C" void kernel_launch(void* const* d_in, const int* in_sizes, int n_in,
                              void* d_out, int out_size, void* d_ws, size_t ws_size,
                              hipStream_t stream)
{
    const float* query = (const float*)d_in[0];
    const float* kvin  = (const float*)d_in[1];
    const float* Wq = (const float*)d_in[2];
    const float* bq = (const float*)d_in[3];
    const float* Wk = (const float*)d_in[4];
    const float* bk = (const float*)d_in[5];
    const float* Wv = (const float*)d_in[6];
    const float* bv = (const float*)d_in[7];
    const float* Wo = (const float*)d_in[8];
    const float* bo = (const float*)d_in[9];

    const int M = 8192, D = 1024;   // M = B*SQ = B*SKV
    u16* Qb = (u16*)d_ws;
    u16* Kb = Qb + (size_t)M * D;
    u16* Vb = Kb + (size_t)M * D;
    u16* Ob = Vb + (size_t)M * D;   // total 64 MB of d_ws

    dim3 gg(M / 64, D / 64);
    gemm_bias_64<true,  true ><<<gg, 256, 0, stream>>>(query, Wq, bq, Qb, M, D, D);
    gemm_bias_64<true,  true ><<<gg, 256, 0, stream>>>(kvin,  Wk, bk, Kb, M, D, D);
    gemm_bias_64<true,  true ><<<gg, 256, 0, stream>>>(kvin,  Wv, bv, Vb, M, D, D);
    attn_fwd<<<dim3(32, 64), 256, 0, stream>>>(Qb, Kb, Vb, Ob);
    gemm_bias_64<false, false><<<gg, 256, 0, stream>>>(Ob, Wo, bo, (float*)d_out, M, D, D);
}

// Round 2
// 275.165 us; speedup vs baseline: 1.8933x; 1.8933x over previous
//
#include <hip/hip_runtime.h>

// CrossAttention B=4, S=2048, D=H=1024, NH=16, HD=64.
// Fast path (ws>=66MB): cvt fp32->bf16 (into d_out scratch), transpose weights
// (2MB ws slot), 128x128 global_load_lds GEMMs, swapped-QK 32x32 flash attn.
// Fallback (ws>=64MB): round-1 64x64 GEMMs + same new attention.

typedef short s16x8 __attribute__((ext_vector_type(8)));
typedef short s16x4 __attribute__((ext_vector_type(4)));
typedef float f32x4 __attribute__((ext_vector_type(4)));
typedef float f32x16 __attribute__((ext_vector_type(16)));
typedef unsigned short u16;
typedef unsigned int u32;

__device__ __forceinline__ u16 f2bf(float f){
    union{float f;u32 u;} v; v.f=f;
    u32 r = v.u + 0x7fffu + ((v.u>>16)&1u);
    return (u16)(r>>16);
}
__device__ __forceinline__ u32 pkbf(float lo,float hi){ // two bf16 packed (round-half-up)
    union{float f;u32 u;} a,b; a.f=lo; b.f=hi;
    return ((a.u+0x8000u)>>16) | ((b.u+0x8000u)&0xffff0000u);
}
// 128B-row LDS tile, XOR swizzle on bits 4..6 (kills column-slice conflicts)
__device__ __forceinline__ int swz(int row,int colB){ return row*128 + (colB ^ ((row&7)<<4)); }

__device__ __forceinline__ void gl16(const void* g, void* l){
    __builtin_amdgcn_global_load_lds((__attribute__((address_space(1))) void*)(void*)g,
                                     (__attribute__((address_space(3))) void*)l, 16, 0, 0);
}

#define QSCALE 0.1803368801111204f  /* log2(e)/sqrt(64) */

// ---------------- fp32 -> bf16 elementwise (8 elems/thread, exact grid) ----
__global__ __launch_bounds__(256) void cvtbf(const float* __restrict__ in, u16* __restrict__ out){
    size_t i = ((size_t)blockIdx.x*256 + threadIdx.x)*8;
    f32x4 a = *(const f32x4*)(in+i), b = *(const f32x4*)(in+i+4);
    s16x8 o;
    #pragma unroll
    for (int j=0;j<4;++j){ o[j]=(short)f2bf(a[j]); o[4+j]=(short)f2bf(b[j]); }
    *(s16x8*)(out+i) = o;
}

// ---------------- W[1024][1024] fp32 -> Wt[n][k] bf16 ----------------------
__global__ __launch_bounds__(256) void transW(const float* __restrict__ W, u16* __restrict__ Wt){
    __shared__ u16 T[64*68];
    const int tid = threadIdx.x;
    const int n0 = blockIdx.x*64, k0 = blockIdx.y*64;
    const int tr = tid>>4, tc = (tid&15)*4;
    #pragma unroll
    for (int p=0;p<4;++p){
        int k = p*16 + tr;
        f32x4 v = *(const f32x4*)(W + (size_t)(k0+k)*1024 + n0 + tc);
        s16x4 o;
        #pragma unroll
        for (int j=0;j<4;++j) o[j]=(short)f2bf(v[j]);
        *(s16x4*)(T + k*68 + tc) = o;
    }
    __syncthreads();
    #pragma unroll
    for (int p=0;p<4;++p){
        int n = p*16 + tr;
        s16x4 o;
        #pragma unroll
        for (int e=0;e<4;++e) o[e] = (short)T[(tc+e)*68 + n];
        *(s16x4*)(Wt + (size_t)(n0+n)*1024 + k0 + tc) = o;
    }
}

// ---------------- fast GEMM: C = A[M,K](bf16) @ Bt[N,K]^T(bf16) + bias -----
// 128x128 tile, BK=64, 4 waves (2x2), global_load_lds x16B staging.
// EPI: 0 = bf16 out, (acc+bias)*scale ; 2 = bf16 V-transposed ; 3 = f32 out
template<int EPI>
__global__ __launch_bounds__(256)
void gemm128(const u16* __restrict__ A, const u16* __restrict__ Bt,
             const float* __restrict__ bias, void* __restrict__ C,
             int M, int N, int K, float scale)
{
    __shared__ __align__(16) u16 As[128*64];
    __shared__ __align__(16) u16 Bs[128*64];
    const int tid = threadIdx.x, lane = tid&63, wave = tid>>6;
    const int ln = lane&15, g = lane>>4;
    const int wm = wave>>1, wn = wave&1;
    const int bm = blockIdx.x, bn = blockIdx.y;

    f32x4 acc[4][4] = {};

    for (int k0=0; k0<K; k0+=64){
        #pragma unroll
        for (int i=0;i<4;++i){
            int c = i*256 + tid;
            int row = c>>3, cc = c&7;
            gl16(A  + (size_t)(bm*128+row)*K + k0 + cc*8, (char*)As + (size_t)c*16);
            gl16(Bt + (size_t)(bn*128+row)*K + k0 + cc*8, (char*)Bs + (size_t)c*16);
        }
        __syncthreads();
        #pragma unroll
        for (int kk=0;kk<2;++kk){
            s16x8 af[4], bf[4];
            #pragma unroll
            for (int mi=0;mi<4;++mi)
                af[mi] = *(const s16x8*)((const char*)As + (size_t)(wm*64+mi*16+ln)*128 + kk*64 + g*16);
            #pragma unroll
            for (int ni=0;ni<4;++ni)
                bf[ni] = *(const s16x8*)((const char*)Bs + (size_t)(wn*64+ni*16+ln)*128 + kk*64 + g*16);
            #pragma unroll
            for (int mi=0;mi<4;++mi)
                #pragma unroll
                for (int ni=0;ni<4;++ni)
                    acc[mi][ni] = __builtin_amdgcn_mfma_f32_16x16x32_bf16(af[mi], bf[ni], acc[mi][ni], 0,0,0);
        }
        __syncthreads();
    }

    #pragma unroll
    for (int mi=0;mi<4;++mi){
        #pragma unroll
        for (int ni=0;ni<4;++ni){
            int col = bn*128 + wn*64 + ni*16 + ln;
            float bv = bias[col];
            #pragma unroll
            for (int r=0;r<4;++r){
                int row = bm*128 + wm*64 + mi*16 + 4*g + r;
                float v = (acc[mi][ni][r] + bv) * scale;
                if constexpr (EPI==0)
                    ((u16*)C)[(size_t)row*N + col] = f2bf(v);
                else if constexpr (EPI==2){
                    int b = row>>11, s = row&2047;
                    ((u16*)C)[((size_t)(b*1024 + col))*2048 + s] = f2bf(v);
                } else
                    ((float*)C)[(size_t)row*N + col] = v;
            }
        }
    }
}

// ---------------- fallback GEMM (round-1 64x64, fp32-A capable) ------------
template<bool A_IS_F32, int EPI>
__global__ __launch_bounds__(256)
void gemm_bias_64(const void* __restrict__ Av, const float* __restrict__ W,
                  const float* __restrict__ bias, void* __restrict__ Cout,
                  int M, int N, int K, float scale)
{
    __shared__ __align__(16) char smem[16384];
    char* As = smem;
    char* Ws = smem + 8192;
    const int tid  = threadIdx.x;
    const int lane = tid & 63, wave = tid >> 6;
    const int g = lane >> 4, ln = lane & 15;
    const int wm = wave >> 1, wn = wave & 1;
    const int bm = blockIdx.x, bn = blockIdx.y;
    f32x4 acc[2][2] = {};
    const int srow = tid >> 2;
    const int sch  = (tid & 3) * 16;

    for (int k0 = 0; k0 < K; k0 += 64) {
        if constexpr (A_IS_F32) {
            const float* a = (const float*)Av + (size_t)(bm*64+srow)*K + k0 + sch;
            const f32x4* a4 = (const f32x4*)a;
            #pragma unroll
            for (int c = 0; c < 2; ++c) {
                f32x4 x = a4[c*2+0], y = a4[c*2+1];
                s16x8 wv;
                #pragma unroll
                for (int j = 0; j < 4; ++j){ wv[j]=(short)f2bf(x[j]); wv[4+j]=(short)f2bf(y[j]); }
                *(s16x8*)(As + swz(srow, sch*2 + c*16)) = wv;
            }
        } else {
            const u16* a = (const u16*)Av + (size_t)(bm*64+srow)*K + k0 + sch;
            *(s16x8*)(As + swz(srow, sch*2 + 0))  = *(const s16x8*)(a + 0);
            *(s16x8*)(As + swz(srow, sch*2 + 16)) = *(const s16x8*)(a + 8);
        }
        {
            const float* wsrc = W + (size_t)(k0+srow)*N + bn*64 + sch;
            #pragma unroll
            for (int j = 0; j < 16; ++j) {
                int n = sch + j;
                *(short*)(Ws + n*128 + ((srow*2) ^ ((n&7)<<4))) = (short)f2bf(wsrc[j]);
            }
        }
        __syncthreads();
        #pragma unroll
        for (int kk = 0; kk < 2; ++kk) {
            s16x8 af[2], bfr[2];
            #pragma unroll
            for (int mi = 0; mi < 2; ++mi)
                af[mi] = *(const s16x8*)(As + swz(wm*32+mi*16+ln, kk*64 + g*16));
            #pragma unroll
            for (int ni = 0; ni < 2; ++ni)
                bfr[ni] = *(const s16x8*)(Ws + swz(wn*32+ni*16+ln, kk*64 + g*16));
            #pragma unroll
            for (int mi = 0; mi < 2; ++mi)
                #pragma unroll
                for (int ni = 0; ni < 2; ++ni)
                    acc[mi][ni] = __builtin_amdgcn_mfma_f32_16x16x32_bf16(af[mi], bfr[ni], acc[mi][ni], 0,0,0);
        }
        __syncthreads();
    }
    #pragma unroll
    for (int mi = 0; mi < 2; ++mi){
        #pragma unroll
        for (int ni = 0; ni < 2; ++ni){
            int col = bn*64 + wn*32 + ni*16 + ln;
            float bv = bias[col];
            #pragma unroll
            for (int r = 0; r < 4; ++r){
                int row = bm*64 + wm*32 + mi*16 + 4*g + r;
                float v = (acc[mi][ni][r] + bv) * scale;
                if constexpr (EPI==0)
                    ((u16*)Cout)[(size_t)row*N + col] = f2bf(v);
                else if constexpr (EPI==2){
                    int b = row>>11, s = row&2047;
                    ((u16*)Cout)[((size_t)(b*1024+col))*2048 + s] = f2bf(v);
                } else
                    ((float*)Cout)[(size_t)row*N + col] = v;
            }
        }
    }
}

// ---------------- flash attention, swapped-QK, 32x32 MFMA ------------------
// Block = 128 q rows of one (b,h); 4 waves x 32 q. KV tiles of 64.
// Q is pre-scaled by log2(e)/sqrt(HD) in the Q-projection epilogue.
// S^T = mfma(K, Q): lane owns column q = lane&31; softmax in-register.
// PV: O^T = mfma(Vt, P^T) so the O rescale factor is lane-uniform.
__global__ __launch_bounds__(256)
void attn_fwd2(const u16* __restrict__ Q, const u16* __restrict__ K,
               const u16* __restrict__ Vt, u16* __restrict__ O)
{
    __shared__ __align__(16) char smem[16384];
    char* Ks = smem;         // [64 kv][64 d]  swizzled 128B rows
    char* Vs = smem + 8192;  // [64 d][64 kv]  swizzled
    const int tid = threadIdx.x, lane = tid&63, wave = tid>>6;
    const int l31 = lane&31, hl = lane>>5;
    const int qt = blockIdx.x, bh = blockIdx.y;
    const int b = bh>>4, h = bh&15;

    const int qrow = qt*128 + wave*32 + l31;
    const size_t qgoff = ((size_t)(b*2048 + qrow))*1024 + h*64;
    const u16* Kgp = K  + ((size_t)(b*2048))*1024 + h*64;
    const u16* Vgp = Vt + ((size_t)(b*1024 + h*64))*2048;

    // Q as B-frag: col=q=l31, k=d=16ks+8hl+j
    s16x8 bq[4];
    #pragma unroll
    for (int ks=0;ks<4;++ks)
        bq[ks] = *(const s16x8*)(Q + qgoff + 16*ks + 8*hl);

    float m_run = -1e30f, l_run = 0.0f;
    f32x16 oa[2] = {};   // O^T: fd picks d 0..31 / 32..63 rows; col q = l31

    const int srow = tid>>2, sch = (tid&3)*16;

    for (int kt=0; kt<32; ++kt){
        const int kv0 = kt*64;
        {   // stage K[kv][d] and Vt[d][kv] tiles (vector, swizzled)
            const u16* ksrc = Kgp + (size_t)(kv0+srow)*1024 + sch;
            *(s16x8*)(Ks + swz(srow, 2*sch))    = *(const s16x8*)(ksrc);
            *(s16x8*)(Ks + swz(srow, 2*sch+16)) = *(const s16x8*)(ksrc+8);
            const u16* vsrc = Vgp + (size_t)srow*2048 + kv0 + sch;
            *(s16x8*)(Vs + swz(srow, 2*sch))    = *(const s16x8*)(vsrc);
            *(s16x8*)(Vs + swz(srow, 2*sch+16)) = *(const s16x8*)(vsrc+8);
        }
        __syncthreads();

        // S^T[kv][q]
        f32x16 sS[2] = {};
        #pragma unroll
        for (int fkv=0; fkv<2; ++fkv){
            #pragma unroll
            for (int ks=0; ks<4; ++ks){
                s16x8 ak = *(const s16x8*)(Ks + swz(fkv*32 + l31, 32*ks + 16*hl));
                sS[fkv] = __builtin_amdgcn_mfma_f32_32x32x16_bf16(ak, bq[ks], sS[fkv], 0,0,0);
            }
        }

        // in-register softmax for q = l31 (pair partner = lane^32)
        float mx[8];
        #pragma unroll
        for (int i=0;i<8;++i)
            mx[i] = fmaxf(fmaxf(sS[0][i], sS[0][i+8]), fmaxf(sS[1][i], sS[1][i+8]));
        float pm = fmaxf(fmaxf(fmaxf(mx[0],mx[1]),fmaxf(mx[2],mx[3])),
                         fmaxf(fmaxf(mx[4],mx[5]),fmaxf(mx[6],mx[7])));
        pm = fmaxf(pm, __shfl_xor(pm, 32));
        float mn  = fmaxf(m_run, pm);
        float scl = __builtin_amdgcn_exp2f(m_run - mn);
        #pragma unroll
        for (int f=0; f<2; ++f)
            #pragma unroll
            for (int r=0; r<16; ++r)
                sS[f][r] = __builtin_amdgcn_exp2f(sS[f][r] - mn);
        float sm[8];
        #pragma unroll
        for (int i=0;i<8;++i) sm[i] = (sS[0][i]+sS[0][i+8]) + (sS[1][i]+sS[1][i+8]);
        float rs = ((sm[0]+sm[1])+(sm[2]+sm[3])) + ((sm[4]+sm[5])+(sm[6]+sm[7]));
        rs += __shfl_xor(rs, 32);
        l_run = l_run*scl + rs;
        m_run = mn;
        oa[0] *= scl; oa[1] *= scl;

        // pack P^T to bf16 words: Wp[f][w] = (kv pair 16f.. at rows (2w,2w+1))
        u32 Wp[2][8];
        #pragma unroll
        for (int f=0; f<2; ++f)
            #pragma unroll
            for (int w=0; w<8; ++w)
                Wp[f][w] = pkbf(sS[f][2*w], sS[f][2*w+1]);

        // build PV B-frags: bP[ks] holds P[kv=16ks+8hl+j][q=l31], j=0..7
        s16x8 bP[4];
        #pragma unroll
        for (int ks=0; ks<4; ++ks){
            const int f = ks>>1, base = 4*(ks&1);
            u32 own0 = hl ? Wp[f][base+2] : Wp[f][base+0];
            u32 own1 = hl ? Wp[f][base+3] : Wp[f][base+1];
            u32 snd0 = hl ? Wp[f][base+0] : Wp[f][base+2];
            u32 snd1 = hl ? Wp[f][base+1] : Wp[f][base+3];
            u32 rcv0 = (u32)__shfl_xor((int)snd0, 32);
            u32 rcv1 = (u32)__shfl_xor((int)snd1, 32);
            union { u32 w[4]; s16x8 v; } u;
            u.w[0] = hl ? rcv0 : own0;
            u.w[1] = hl ? rcv1 : own1;
            u.w[2] = hl ? own0 : rcv0;
            u.w[3] = hl ? own1 : rcv1;
            bP[ks] = u.v;
        }

        // O^T += Vt-frag x P^T
        #pragma unroll
        for (int fd=0; fd<2; ++fd){
            #pragma unroll
            for (int ks=0; ks<4; ++ks){
                s16x8 av = *(const s16x8*)(Vs + swz(fd*32 + l31, 32*ks + 16*hl));
                oa[fd] = __builtin_amdgcn_mfma_f32_32x32x16_bf16(av, bP[ks], oa[fd], 0,0,0);
            }
        }
        __syncthreads();
    }

    // epilogue: O[q][d], d = fd*32 + 8*rq + 4*hl + e
    float inv = 1.0f / l_run;
    u16* Ob = O + qgoff;
    #pragma unroll
    for (int fd=0; fd<2; ++fd){
        #pragma unroll
        for (int rq=0; rq<4; ++rq){
            s16x4 o;
            #pragma unroll
            for (int e=0;e<4;++e) o[e] = (short)f2bf(oa[fd][rq*4+e] * inv);
            *(s16x4*)(Ob + fd*32 + rq*8 + hl*4) = o;
        }
    }
}

extern "C" void kernel_launch(void* const* d_in, const int* in_sizes, int n_in,
                              void* d_out, int out_size, void* d_ws, size_t ws_size,
                              hipStream_t stream)
{
    const float* query = (const float*)d_in[0];
    const float* kvin  = (const float*)d_in[1];
    const float* Wq = (const float*)d_in[2];
    const float* bq = (const float*)d_in[3];
    const float* Wk = (const float*)d_in[4];
    const float* bk = (const float*)d_in[5];
    const float* Wv = (const float*)d_in[6];
    const float* bv = (const float*)d_in[7];
    const float* Wo = (const float*)d_in[8];
    const float* bo = (const float*)d_in[9];

    const int M = 8192, D = 1024;
    const size_t MB = 1024ull*1024ull;
    u16* Qb  = (u16*)d_ws;
    u16* Kb  = Qb  + 8*MB;
    u16* Vtb = Kb  + 8*MB;
    u16* Ob  = Vtb + 8*MB;          // 64 MB

    if (ws_size >= 66*MB) {
        u16* Wt   = Ob + 8*MB;      // ws[64MB..66MB)
        u16* qbf  = (u16*)d_out;    // d_out used as 32MB scratch until final GEMM
        u16* kvbf = qbf + 8*MB;

        cvtbf<<<4096,256,0,stream>>>(query, qbf);
        cvtbf<<<4096,256,0,stream>>>(kvin,  kvbf);

        dim3 tg(16,16), gg(64,8);
        transW<<<tg,256,0,stream>>>(Wq, Wt);
        gemm128<0><<<gg,256,0,stream>>>(qbf,  Wt, bq, Qb,  M, D, D, QSCALE);
        transW<<<tg,256,0,stream>>>(Wk, Wt);
        gemm128<0><<<gg,256,0,stream>>>(kvbf, Wt, bk, Kb,  M, D, D, 1.0f);
        transW<<<tg,256,0,stream>>>(Wv, Wt);
        gemm128<2><<<gg,256,0,stream>>>(kvbf, Wt, bv, Vtb, M, D, D, 1.0f);

        attn_fwd2<<<dim3(16,64),256,0,stream>>>(Qb, Kb, Vtb, Ob);

        transW<<<tg,256,0,stream>>>(Wo, Wt);
        gemm128<3><<<gg,256,0,stream>>>(Ob, Wt, bo, d_out, M, D, D, 1.0f);
    } else {
        dim3 gg(128,16);
        gemm_bias_64<true ,0><<<gg,256,0,stream>>>(query, Wq, bq, Qb,  M, D, D, QSCALE);
        gemm_bias_64<true ,0><<<gg,256,0,stream>>>(kvin,  Wk, bk, Kb,  M, D, D, 1.0f);
        gemm_bias_64<true ,2><<<gg,256,0,stream>>>(kvin,  Wv, bv, Vtb, M, D, D, 1.0f);
        attn_fwd2<<<dim3(16,64),256,0,stream>>>(Qb, Kb, Vtb, Ob);
        gemm_bias_64<false,3><<<gg,256,0,stream>>>(Ob, Wo, bo, d_out, M, D, D, 1.0f);
    }
}

// Round 3
// 244.755 us; speedup vs baseline: 2.1285x; 1.1242x over previous
//
#include <hip/hip_runtime.h>

// CrossAttention B=4, S=2048, D=H=1024, NH=16, HD=64.
// R3: attn = cvt_pk+permlane32_swap P-pack, defer-max, global_load_lds dbuf
//     staging (1 barrier/tile), setprio around MFMA, XCD-chunked grid remap.
//     gemm128 = 2-phase double-buffered global_load_lds.

typedef short s16x8 __attribute__((ext_vector_type(8)));
typedef short s16x4 __attribute__((ext_vector_type(4)));
typedef float f32x4 __attribute__((ext_vector_type(4)));
typedef float f32x16 __attribute__((ext_vector_type(16)));
typedef unsigned short u16;
typedef unsigned int u32;

__device__ __forceinline__ u16 f2bf(float f){
    union{float f;u32 u;} v; v.f=f;
    u32 r = v.u + 0x7fffu + ((v.u>>16)&1u);
    return (u16)(r>>16);
}
// 128B-row LDS tile; XOR swizzle on bits 4..6
__device__ __forceinline__ int swz(int row,int colB){ return row*128 + (colB ^ ((row&7)<<4)); }

__device__ __forceinline__ void gl16(const void* g, void* l){
    __builtin_amdgcn_global_load_lds((__attribute__((address_space(1))) void*)(void*)g,
                                     (__attribute__((address_space(3))) void*)l, 16, 0, 0);
}
__device__ __forceinline__ u32 cvtpk(float lo, float hi){
    u32 r; asm("v_cvt_pk_bf16_f32 %0, %1, %2" : "=v"(r) : "v"(lo), "v"(hi)); return r;
}
__device__ __forceinline__ void plswap(u32& a, u32& b){
    asm("v_permlane32_swap_b32 %0, %1" : "+v"(a), "+v"(b));
}

#define QSCALE 0.1803368801111204f  /* log2(e)/sqrt(64) */

// ---------------- fp32 -> bf16 elementwise ----------------
__global__ __launch_bounds__(256) void cvtbf(const float* __restrict__ in, u16* __restrict__ out){
    size_t i = ((size_t)blockIdx.x*256 + threadIdx.x)*8;
    f32x4 a = *(const f32x4*)(in+i), b = *(const f32x4*)(in+i+4);
    s16x8 o;
    #pragma unroll
    for (int j=0;j<4;++j){ o[j]=(short)f2bf(a[j]); o[4+j]=(short)f2bf(b[j]); }
    *(s16x8*)(out+i) = o;
}

// ---------------- W[1024][1024] fp32 -> Wt[n][k] bf16 ----------------
__global__ __launch_bounds__(256) void transW(const float* __restrict__ W, u16* __restrict__ Wt){
    __shared__ u16 T[64*68];
    const int tid = threadIdx.x;
    const int n0 = blockIdx.x*64, k0 = blockIdx.y*64;
    const int tr = tid>>4, tc = (tid&15)*4;
    #pragma unroll
    for (int p=0;p<4;++p){
        int k = p*16 + tr;
        f32x4 v = *(const f32x4*)(W + (size_t)(k0+k)*1024 + n0 + tc);
        s16x4 o;
        #pragma unroll
        for (int j=0;j<4;++j) o[j]=(short)f2bf(v[j]);
        *(s16x4*)(T + k*68 + tc) = o;
    }
    __syncthreads();
    #pragma unroll
    for (int p=0;p<4;++p){
        int n = p*16 + tr;
        s16x4 o;
        #pragma unroll
        for (int e=0;e<4;++e) o[e] = (short)T[(tc+e)*68 + n];
        *(s16x4*)(Wt + (size_t)(n0+n)*1024 + k0 + tc) = o;
    }
}

// ---------------- GEMM: C = A[M,K](bf16) @ Bt[N,K]^T(bf16) + bias ----------
// 128x128 tile, BK=64, 2-phase double buffer, global_load_lds x16.
// EPI: 0 bf16 out ; 2 bf16 V-transposed ; 3 f32 out
template<int EPI>
__global__ __launch_bounds__(256)
void gemm128(const u16* __restrict__ A, const u16* __restrict__ Bt,
             const float* __restrict__ bias, void* __restrict__ C,
             int M, int N, int K, float scale)
{
    __shared__ __align__(16) u16 As[2][128*64];
    __shared__ __align__(16) u16 Bs[2][128*64];
    const int tid = threadIdx.x, lane = tid&63, wave = tid>>6;
    const int ln = lane&15, g = lane>>4;
    const int wm = wave>>1, wn = wave&1;
    const int bm = blockIdx.x, bn = blockIdx.y;

    f32x4 acc[4][4] = {};

    auto stage = [&](int k0, int buf){
        #pragma unroll
        for (int i=0;i<4;++i){
            int c = i*256 + tid;
            int row = c>>3, cc = c&7;
            gl16(A  + (size_t)(bm*128+row)*K + k0 + cc*8, (char*)As[buf] + (size_t)c*16);
            gl16(Bt + (size_t)(bn*128+row)*K + k0 + cc*8, (char*)Bs[buf] + (size_t)c*16);
        }
    };

    stage(0, 0);
    __syncthreads();
    int cur = 0;
    for (int k0=0; k0<K; k0+=64){
        if (k0+64 < K) stage(k0+64, cur^1);
        #pragma unroll
        for (int kk=0;kk<2;++kk){
            s16x8 af[4], bf[4];
            #pragma unroll
            for (int mi=0;mi<4;++mi)
                af[mi] = *(const s16x8*)((const char*)As[cur] + (size_t)(wm*64+mi*16+ln)*128 + kk*64 + g*16);
            #pragma unroll
            for (int ni=0;ni<4;++ni)
                bf[ni] = *(const s16x8*)((const char*)Bs[cur] + (size_t)(wn*64+ni*16+ln)*128 + kk*64 + g*16);
            #pragma unroll
            for (int mi=0;mi<4;++mi)
                #pragma unroll
                for (int ni=0;ni<4;++ni)
                    acc[mi][ni] = __builtin_amdgcn_mfma_f32_16x16x32_bf16(af[mi], bf[ni], acc[mi][ni], 0,0,0);
        }
        __syncthreads();
        cur ^= 1;
    }

    #pragma unroll
    for (int mi=0;mi<4;++mi){
        #pragma unroll
        for (int ni=0;ni<4;++ni){
            int col = bn*128 + wn*64 + ni*16 + ln;
            float bv = bias[col];
            #pragma unroll
            for (int r=0;r<4;++r){
                int row = bm*128 + wm*64 + mi*16 + 4*g + r;
                float v = (acc[mi][ni][r] + bv) * scale;
                if constexpr (EPI==0)
                    ((u16*)C)[(size_t)row*N + col] = f2bf(v);
                else if constexpr (EPI==2){
                    int b = row>>11, s = row&2047;
                    ((u16*)C)[((size_t)(b*1024 + col))*2048 + s] = f2bf(v);
                } else
                    ((float*)C)[(size_t)row*N + col] = v;
            }
        }
    }
}

// ---------------- fallback GEMM (64x64, fp32-A capable) ----------------
template<bool A_IS_F32, int EPI>
__global__ __launch_bounds__(256)
void gemm_bias_64(const void* __restrict__ Av, const float* __restrict__ W,
                  const float* __restrict__ bias, void* __restrict__ Cout,
                  int M, int N, int K, float scale)
{
    __shared__ __align__(16) char smem[16384];
    char* As = smem;
    char* Ws = smem + 8192;
    const int tid  = threadIdx.x;
    const int lane = tid & 63, wave = tid >> 6;
    const int g = lane >> 4, ln = lane & 15;
    const int wm = wave >> 1, wn = wave & 1;
    const int bm = blockIdx.x, bn = blockIdx.y;
    f32x4 acc[2][2] = {};
    const int srow = tid >> 2;
    const int sch  = (tid & 3) * 16;

    for (int k0 = 0; k0 < K; k0 += 64) {
        if constexpr (A_IS_F32) {
            const float* a = (const float*)Av + (size_t)(bm*64+srow)*K + k0 + sch;
            const f32x4* a4 = (const f32x4*)a;
            #pragma unroll
            for (int c = 0; c < 2; ++c) {
                f32x4 x = a4[c*2+0], y = a4[c*2+1];
                s16x8 wv;
                #pragma unroll
                for (int j = 0; j < 4; ++j){ wv[j]=(short)f2bf(x[j]); wv[4+j]=(short)f2bf(y[j]); }
                *(s16x8*)(As + swz(srow, sch*2 + c*16)) = wv;
            }
        } else {
            const u16* a = (const u16*)Av + (size_t)(bm*64+srow)*K + k0 + sch;
            *(s16x8*)(As + swz(srow, sch*2 + 0))  = *(const s16x8*)(a + 0);
            *(s16x8*)(As + swz(srow, sch*2 + 16)) = *(const s16x8*)(a + 8);
        }
        {
            const float* wsrc = W + (size_t)(k0+srow)*N + bn*64 + sch;
            #pragma unroll
            for (int j = 0; j < 16; ++j) {
                int n = sch + j;
                *(short*)(Ws + n*128 + ((srow*2) ^ ((n&7)<<4))) = (short)f2bf(wsrc[j]);
            }
        }
        __syncthreads();
        #pragma unroll
        for (int kk = 0; kk < 2; ++kk) {
            s16x8 af[2], bfr[2];
            #pragma unroll
            for (int mi = 0; mi < 2; ++mi)
                af[mi] = *(const s16x8*)(As + swz(wm*32+mi*16+ln, kk*64 + g*16));
            #pragma unroll
            for (int ni = 0; ni < 2; ++ni)
                bfr[ni] = *(const s16x8*)(Ws + swz(wn*32+ni*16+ln, kk*64 + g*16));
            #pragma unroll
            for (int mi = 0; mi < 2; ++mi)
                #pragma unroll
                for (int ni = 0; ni < 2; ++ni)
                    acc[mi][ni] = __builtin_amdgcn_mfma_f32_16x16x32_bf16(af[mi], bfr[ni], acc[mi][ni], 0,0,0);
        }
        __syncthreads();
    }
    #pragma unroll
    for (int mi = 0; mi < 2; ++mi){
        #pragma unroll
        for (int ni = 0; ni < 2; ++ni){
            int col = bn*64 + wn*32 + ni*16 + ln;
            float bv = bias[col];
            #pragma unroll
            for (int r = 0; r < 4; ++r){
                int row = bm*64 + wm*32 + mi*16 + 4*g + r;
                float v = (acc[mi][ni][r] + bv) * scale;
                if constexpr (EPI==0)
                    ((u16*)Cout)[(size_t)row*N + col] = f2bf(v);
                else if constexpr (EPI==2){
                    int b = row>>11, s = row&2047;
                    ((u16*)Cout)[((size_t)(b*1024+col))*2048 + s] = f2bf(v);
                } else
                    ((float*)Cout)[(size_t)row*N + col] = v;
            }
        }
    }
}

// ---------------- flash attention, swapped-QK, 32x32 MFMA ----------------
// 128 q rows per block (4 waves x 32 q). KV tiles of 64, double-buffered
// global_load_lds staging with pre-swizzled source. Q pre-scaled by
// log2(e)/sqrt(HD). Lane owns q-column l31; softmax fully in-register.
__global__ __launch_bounds__(256)
void attn_fwd3(const u16* __restrict__ Q, const u16* __restrict__ K,
               const u16* __restrict__ Vt, u16* __restrict__ O)
{
    __shared__ __align__(16) char smem[32768];   // [K0 8K][V0 8K][K1 8K][V1 8K]
    const int tid = threadIdx.x, lane = tid&63, wave = tid>>6;
    const int l31 = lane&31, hl = lane>>5;

    // XCD-chunked remap: XCD c handles bh in [8c, 8c+8) (K/V L2 reuse)
    int dlin = blockIdx.y*16 + blockIdx.x;
    int xc = dlin&7, t = dlin>>3;
    int bh = xc*8 + (t>>4), qt = t&15;
    int b = bh>>4, h = bh&15;

    const int qrow = qt*128 + wave*32 + l31;
    const size_t qgoff = ((size_t)(b*2048 + qrow))*1024 + h*64;
    const u16* Kg = K  + ((size_t)(b*2048))*1024 + h*64;
    const u16* Vg = Vt + ((size_t)(b*1024 + h*64))*2048;

    s16x8 bq[4];
    #pragma unroll
    for (int ks=0;ks<4;++ks)
        bq[ks] = *(const s16x8*)(Q + qgoff + 16*ks + 8*hl);

    float m_run = -1e30f, l_run = 0.0f;
    f32x16 oa0 = {}, oa1 = {};

    // staging: chunk c (0..511): row=c>>3, phys col-chunk c&7 holds logical
    // chunk (c&7)^(row&7) so that swizzled reads see logical data.
    auto stage = [&](int kt, int buf){
        char* Kb = smem + buf*16384;
        char* Vb = Kb + 8192;
        const int kv0 = kt*64;
        #pragma unroll
        for (int i=0;i<2;++i){
            int c = i*256 + tid;
            int row = c>>3;
            int q = (c&7) ^ (row&7);
            gl16(Kg + (size_t)(kv0+row)*1024 + q*8, Kb + c*16);
            gl16(Vg + (size_t)row*2048 + kv0 + q*8, Vb + c*16);
        }
    };

    stage(0, 0);
    __syncthreads();
    int cur = 0;

    for (int kt=0; kt<32; ++kt){
        if (kt+1 < 32) stage(kt+1, cur^1);
        char* Kb = smem + cur*16384;
        char* Vb = Kb + 8192;

        // S^T[kv][q] = K-frag x Q-frag
        f32x16 s0 = {}, s1 = {};
        __builtin_amdgcn_s_setprio(1);
        #pragma unroll
        for (int ks=0; ks<4; ++ks){
            s16x8 ak0 = *(const s16x8*)(Kb + swz(l31,      32*ks + 16*hl));
            s16x8 ak1 = *(const s16x8*)(Kb + swz(32 + l31, 32*ks + 16*hl));
            s0 = __builtin_amdgcn_mfma_f32_32x32x16_bf16(ak0, bq[ks], s0, 0,0,0);
            s1 = __builtin_amdgcn_mfma_f32_32x32x16_bf16(ak1, bq[ks], s1, 0,0,0);
        }
        __builtin_amdgcn_s_setprio(0);

        // row max (tree) + partner
        float tm[8];
        #pragma unroll
        for (int i=0;i<8;++i) tm[i] = fmaxf(fmaxf(s0[i], s0[i+8]), fmaxf(s1[i], s1[i+8]));
        float pm = fmaxf(fmaxf(fmaxf(tm[0],tm[1]),fmaxf(tm[2],tm[3])),
                         fmaxf(fmaxf(tm[4],tm[5]),fmaxf(tm[6],tm[7])));
        pm = fmaxf(pm, __shfl_xor(pm, 32));

        // defer-max: rescale only when the wave really needs it
        if (!__all(pm - m_run <= 8.0f)){
            float mn  = fmaxf(m_run, pm);
            float scl = __builtin_amdgcn_exp2f(m_run - mn);
            oa0 *= scl; oa1 *= scl;
            l_run *= scl;
            m_run = mn;
        }

        // P = exp2(S - m_run)
        #pragma unroll
        for (int r=0; r<16; ++r){
            s0[r] = __builtin_amdgcn_exp2f(s0[r] - m_run);
            s1[r] = __builtin_amdgcn_exp2f(s1[r] - m_run);
        }
        // row sum (tree) + partner
        float ts[8];
        #pragma unroll
        for (int i=0;i<8;++i) ts[i] = (s0[i]+s0[i+8]) + (s1[i]+s1[i+8]);
        float rs = ((ts[0]+ts[1])+(ts[2]+ts[3])) + ((ts[4]+ts[5])+(ts[6]+ts[7]));
        rs += __shfl_xor(rs, 32);
        l_run += rs;

        // pack P -> bf16 words, redistribute via permlane32_swap
        // W[w] = pk(s[2w], s[2w+1]); (w0,w2)=swap(W[4s],W[4s+2]), (w1,w3)=swap(W[4s+1],W[4s+3])
        s16x8 bP[4];
        #pragma unroll
        for (int f=0; f<2; ++f){
            const f32x16& sf = f ? s1 : s0;
            u32 W[8];
            #pragma unroll
            for (int w=0; w<8; ++w) W[w] = cvtpk(sf[2*w], sf[2*w+1]);
            #pragma unroll
            for (int s=0; s<2; ++s){
                u32 x0 = W[4*s+0], y0 = W[4*s+2];
                u32 x1 = W[4*s+1], y1 = W[4*s+3];
                plswap(x0, y0);
                plswap(x1, y1);
                union { u32 w[4]; s16x8 v; } u;
                u.w[0]=x0; u.w[1]=x1; u.w[2]=y0; u.w[3]=y1;
                bP[2*f+s] = u.v;
            }
        }

        // O^T += V-frag x P^T
        __builtin_amdgcn_s_setprio(1);
        #pragma unroll
        for (int ks=0; ks<4; ++ks){
            s16x8 av0 = *(const s16x8*)(Vb + swz(l31,      32*ks + 16*hl));
            s16x8 av1 = *(const s16x8*)(Vb + swz(32 + l31, 32*ks + 16*hl));
            oa0 = __builtin_amdgcn_mfma_f32_32x32x16_bf16(av0, bP[ks], oa0, 0,0,0);
            oa1 = __builtin_amdgcn_mfma_f32_32x32x16_bf16(av1, bP[ks], oa1, 0,0,0);
        }
        __builtin_amdgcn_s_setprio(0);

        __syncthreads();
        cur ^= 1;
    }

    // epilogue: O[q][d], d = fd*32 + 8*rq + 4*hl + e
    float inv = 1.0f / l_run;
    u16* Ob = O + qgoff;
    #pragma unroll
    for (int fd=0; fd<2; ++fd){
        const f32x16& oaf = fd ? oa1 : oa0;
        #pragma unroll
        for (int rq=0; rq<4; ++rq){
            s16x4 o;
            #pragma unroll
            for (int e=0;e<4;++e) o[e] = (short)f2bf(oaf[rq*4+e] * inv);
            *(s16x4*)(Ob + fd*32 + rq*8 + hl*4) = o;
        }
    }
}

extern "C" void kernel_launch(void* const* d_in, const int* in_sizes, int n_in,
                              void* d_out, int out_size, void* d_ws, size_t ws_size,
                              hipStream_t stream)
{
    const float* query = (const float*)d_in[0];
    const float* kvin  = (const float*)d_in[1];
    const float* Wq = (const float*)d_in[2];
    const float* bq = (const float*)d_in[3];
    const float* Wk = (const float*)d_in[4];
    const float* bk = (const float*)d_in[5];
    const float* Wv = (const float*)d_in[6];
    const float* bv = (const float*)d_in[7];
    const float* Wo = (const float*)d_in[8];
    const float* bo = (const float*)d_in[9];

    const int M = 8192, D = 1024;
    const size_t MB = 1024ull*1024ull;
    u16* Qb  = (u16*)d_ws;
    u16* Kb  = Qb  + 8*MB;
    u16* Vtb = Kb  + 8*MB;
    u16* Ob  = Vtb + 8*MB;          // 64 MB

    if (ws_size >= 66*MB) {
        u16* Wt   = Ob + 8*MB;      // ws[64MB..66MB)
        u16* qbf  = (u16*)d_out;    // d_out as scratch until final GEMM
        u16* kvbf = qbf + 8*MB;

        cvtbf<<<4096,256,0,stream>>>(query, qbf);
        cvtbf<<<4096,256,0,stream>>>(kvin,  kvbf);

        dim3 tg(16,16), gg(64,8);
        transW<<<tg,256,0,stream>>>(Wq, Wt);
        gemm128<0><<<gg,256,0,stream>>>(qbf,  Wt, bq, Qb,  M, D, D, QSCALE);
        transW<<<tg,256,0,stream>>>(Wk, Wt);
        gemm128<0><<<gg,256,0,stream>>>(kvbf, Wt, bk, Kb,  M, D, D, 1.0f);
        transW<<<tg,256,0,stream>>>(Wv, Wt);
        gemm128<2><<<gg,256,0,stream>>>(kvbf, Wt, bv, Vtb, M, D, D, 1.0f);

        attn_fwd3<<<dim3(16,64),256,0,stream>>>(Qb, Kb, Vtb, Ob);

        transW<<<tg,256,0,stream>>>(Wo, Wt);
        gemm128<3><<<gg,256,0,stream>>>(Ob, Wt, bo, d_out, M, D, D, 1.0f);
    } else {
        dim3 gg(128,16);
        gemm_bias_64<true ,0><<<gg,256,0,stream>>>(query, Wq, bq, Qb,  M, D, D, QSCALE);
        gemm_bias_64<true ,0><<<gg,256,0,stream>>>(kvin,  Wk, bk, Kb,  M, D, D, 1.0f);
        gemm_bias_64<true ,2><<<gg,256,0,stream>>>(kvin,  Wv, bv, Vtb, M, D, D, 1.0f);
        attn_fwd3<<<dim3(16,64),256,0,stream>>>(Qb, Kb, Vtb, Ob);
        gemm_bias_64<false,3><<<gg,256,0,stream>>>(Ob, Wo, bo, d_out, M, D, D, 1.0f);
    }
}

// Round 4
// 235.464 us; speedup vs baseline: 2.2125x; 1.0395x over previous
//
#include <hip/hip_runtime.h>

// CrossAttention B=4, S=2048, D=H=1024, NH=16, HD=64.
// R4: counted-vmcnt double-buffer (no vmcnt(0) drain in-loop) in gemm128 and
//     attn; staging-address hoisting; precomputed swizzled ds offsets.

typedef short s16x8 __attribute__((ext_vector_type(8)));
typedef short s16x4 __attribute__((ext_vector_type(4)));
typedef float f32x4 __attribute__((ext_vector_type(4)));
typedef float f32x16 __attribute__((ext_vector_type(16)));
typedef unsigned short u16;
typedef unsigned int u32;

__device__ __forceinline__ u16 f2bf(float f){
    union{float f;u32 u;} v; v.f=f;
    u32 r = v.u + 0x7fffu + ((v.u>>16)&1u);
    return (u16)(r>>16);
}
// 128B-row LDS tile; XOR swizzle on bits 4..6
__device__ __forceinline__ int swz(int row,int colB){ return row*128 + (colB ^ ((row&7)<<4)); }

__device__ __forceinline__ void gl16(const void* g, void* l){
    __builtin_amdgcn_global_load_lds((__attribute__((address_space(1))) void*)(void*)g,
                                     (__attribute__((address_space(3))) void*)l, 16, 0, 0);
}
__device__ __forceinline__ u32 cvtpk(float lo, float hi){
    u32 r; asm("v_cvt_pk_bf16_f32 %0, %1, %2" : "=v"(r) : "v"(lo), "v"(hi)); return r;
}
__device__ __forceinline__ void plswap(u32& a, u32& b){
    asm("v_permlane32_swap_b32 %0, %1" : "+v"(a), "+v"(b));
}

#define QSCALE 0.1803368801111204f  /* log2(e)/sqrt(64) */

// ---------------- fp32 -> bf16 elementwise ----------------
__global__ __launch_bounds__(256) void cvtbf(const float* __restrict__ in, u16* __restrict__ out){
    size_t i = ((size_t)blockIdx.x*256 + threadIdx.x)*8;
    f32x4 a = *(const f32x4*)(in+i), b = *(const f32x4*)(in+i+4);
    s16x8 o;
    #pragma unroll
    for (int j=0;j<4;++j){ o[j]=(short)f2bf(a[j]); o[4+j]=(short)f2bf(b[j]); }
    *(s16x8*)(out+i) = o;
}

// ---------------- W[1024][1024] fp32 -> Wt[n][k] bf16 ----------------
__global__ __launch_bounds__(256) void transW(const float* __restrict__ W, u16* __restrict__ Wt){
    __shared__ u16 T[64*68];
    const int tid = threadIdx.x;
    const int n0 = blockIdx.x*64, k0 = blockIdx.y*64;
    const int tr = tid>>4, tc = (tid&15)*4;
    #pragma unroll
    for (int p=0;p<4;++p){
        int k = p*16 + tr;
        f32x4 v = *(const f32x4*)(W + (size_t)(k0+k)*1024 + n0 + tc);
        s16x4 o;
        #pragma unroll
        for (int j=0;j<4;++j) o[j]=(short)f2bf(v[j]);
        *(s16x4*)(T + k*68 + tc) = o;
    }
    __syncthreads();
    #pragma unroll
    for (int p=0;p<4;++p){
        int n = p*16 + tr;
        s16x4 o;
        #pragma unroll
        for (int e=0;e<4;++e) o[e] = (short)T[(tc+e)*68 + n];
        *(s16x4*)(Wt + (size_t)(n0+n)*1024 + k0 + tc) = o;
    }
}

// ---------------- GEMM: C = A[M,K](bf16) @ Bt[N,K]^T(bf16) + bias ----------
// 128x128 tile, BK=64, double buffer with counted vmcnt(8) (prefetch stays in
// flight across the barrier), global_load_lds x16.
// EPI: 0 bf16 out ; 2 bf16 V-transposed ; 3 f32 out
template<int EPI>
__global__ __launch_bounds__(256)
void gemm128(const u16* __restrict__ A, const u16* __restrict__ Bt,
             const float* __restrict__ bias, void* __restrict__ C,
             int M, int N, int K, float scale)
{
    __shared__ __align__(16) u16 As[2][128*64];
    __shared__ __align__(16) u16 Bs[2][128*64];
    const int tid = threadIdx.x, lane = tid&63, wave = tid>>6;
    const int ln = lane&15, g = lane>>4;
    const int wm = wave>>1, wn = wave&1;
    const int bm = blockIdx.x, bn = blockIdx.y;

    f32x4 acc[4][4] = {};

    // staging addresses: chunk c=i*256+tid -> row=32i+(tid>>3), col-chunk tid&7
    const int r0g = tid>>3, cc8 = (tid&7)*8;
    const u16* aA = A  + (size_t)(bm*128 + r0g)*K + cc8;
    const u16* aB = Bt + (size_t)(bn*128 + r0g)*K + cc8;

    auto stage = [&](int k0, int buf){
        char* pa = (char*)As[buf] + tid*16;
        char* pb = (char*)Bs[buf] + tid*16;
        #pragma unroll
        for (int i=0;i<4;++i){
            gl16(aA + k0 + i*32*K, pa + i*4096);
            gl16(aB + k0 + i*32*K, pb + i*4096);
        }
    };

    stage(0, 0);
    int cur = 0;
    for (int k0=0; k0<K; k0+=64){
        if (k0+64 < K){
            stage(k0+64, cur^1);
            asm volatile("s_waitcnt vmcnt(8)" ::: "memory");
        } else {
            asm volatile("s_waitcnt vmcnt(0)" ::: "memory");
        }
        __builtin_amdgcn_s_barrier();
        #pragma unroll
        for (int kk=0;kk<2;++kk){
            s16x8 af[4], bf[4];
            #pragma unroll
            for (int mi=0;mi<4;++mi)
                af[mi] = *(const s16x8*)((const char*)As[cur] + (size_t)(wm*64+mi*16+ln)*128 + kk*64 + g*16);
            #pragma unroll
            for (int ni=0;ni<4;++ni)
                bf[ni] = *(const s16x8*)((const char*)Bs[cur] + (size_t)(wn*64+ni*16+ln)*128 + kk*64 + g*16);
            #pragma unroll
            for (int mi=0;mi<4;++mi)
                #pragma unroll
                for (int ni=0;ni<4;++ni)
                    acc[mi][ni] = __builtin_amdgcn_mfma_f32_16x16x32_bf16(af[mi], bf[ni], acc[mi][ni], 0,0,0);
        }
        __builtin_amdgcn_s_barrier();
        cur ^= 1;
    }

    #pragma unroll
    for (int mi=0;mi<4;++mi){
        #pragma unroll
        for (int ni=0;ni<4;++ni){
            int col = bn*128 + wn*64 + ni*16 + ln;
            float bv = bias[col];
            #pragma unroll
            for (int r=0;r<4;++r){
                int row = bm*128 + wm*64 + mi*16 + 4*g + r;
                float v = (acc[mi][ni][r] + bv) * scale;
                if constexpr (EPI==0)
                    ((u16*)C)[(size_t)row*N + col] = f2bf(v);
                else if constexpr (EPI==2){
                    int b = row>>11, s = row&2047;
                    ((u16*)C)[((size_t)(b*1024 + col))*2048 + s] = f2bf(v);
                } else
                    ((float*)C)[(size_t)row*N + col] = v;
            }
        }
    }
}

// ---------------- fallback GEMM (64x64, fp32-A capable) ----------------
template<bool A_IS_F32, int EPI>
__global__ __launch_bounds__(256)
void gemm_bias_64(const void* __restrict__ Av, const float* __restrict__ W,
                  const float* __restrict__ bias, void* __restrict__ Cout,
                  int M, int N, int K, float scale)
{
    __shared__ __align__(16) char smem[16384];
    char* As = smem;
    char* Ws = smem + 8192;
    const int tid  = threadIdx.x;
    const int lane = tid & 63, wave = tid >> 6;
    const int g = lane >> 4, ln = lane & 15;
    const int wm = wave >> 1, wn = wave & 1;
    const int bm = blockIdx.x, bn = blockIdx.y;
    f32x4 acc[2][2] = {};
    const int srow = tid >> 2;
    const int sch  = (tid & 3) * 16;

    for (int k0 = 0; k0 < K; k0 += 64) {
        if constexpr (A_IS_F32) {
            const float* a = (const float*)Av + (size_t)(bm*64+srow)*K + k0 + sch;
            const f32x4* a4 = (const f32x4*)a;
            #pragma unroll
            for (int c = 0; c < 2; ++c) {
                f32x4 x = a4[c*2+0], y = a4[c*2+1];
                s16x8 wv;
                #pragma unroll
                for (int j = 0; j < 4; ++j){ wv[j]=(short)f2bf(x[j]); wv[4+j]=(short)f2bf(y[j]); }
                *(s16x8*)(As + swz(srow, sch*2 + c*16)) = wv;
            }
        } else {
            const u16* a = (const u16*)Av + (size_t)(bm*64+srow)*K + k0 + sch;
            *(s16x8*)(As + swz(srow, sch*2 + 0))  = *(const s16x8*)(a + 0);
            *(s16x8*)(As + swz(srow, sch*2 + 16)) = *(const s16x8*)(a + 8);
        }
        {
            const float* wsrc = W + (size_t)(k0+srow)*N + bn*64 + sch;
            #pragma unroll
            for (int j = 0; j < 16; ++j) {
                int n = sch + j;
                *(short*)(Ws + n*128 + ((srow*2) ^ ((n&7)<<4))) = (short)f2bf(wsrc[j]);
            }
        }
        __syncthreads();
        #pragma unroll
        for (int kk = 0; kk < 2; ++kk) {
            s16x8 af[2], bfr[2];
            #pragma unroll
            for (int mi = 0; mi < 2; ++mi)
                af[mi] = *(const s16x8*)(As + swz(wm*32+mi*16+ln, kk*64 + g*16));
            #pragma unroll
            for (int ni = 0; ni < 2; ++ni)
                bfr[ni] = *(const s16x8*)(Ws + swz(wn*32+ni*16+ln, kk*64 + g*16));
            #pragma unroll
            for (int mi = 0; mi < 2; ++mi)
                #pragma unroll
                for (int ni = 0; ni < 2; ++ni)
                    acc[mi][ni] = __builtin_amdgcn_mfma_f32_16x16x32_bf16(af[mi], bfr[ni], acc[mi][ni], 0,0,0);
        }
        __syncthreads();
    }
    #pragma unroll
    for (int mi = 0; mi < 2; ++mi){
        #pragma unroll
        for (int ni = 0; ni < 2; ++ni){
            int col = bn*64 + wn*32 + ni*16 + ln;
            float bv = bias[col];
            #pragma unroll
            for (int r = 0; r < 4; ++r){
                int row = bm*64 + wm*32 + mi*16 + 4*g + r;
                float v = (acc[mi][ni][r] + bv) * scale;
                if constexpr (EPI==0)
                    ((u16*)Cout)[(size_t)row*N + col] = f2bf(v);
                else if constexpr (EPI==2){
                    int b = row>>11, s = row&2047;
                    ((u16*)Cout)[((size_t)(b*1024+col))*2048 + s] = f2bf(v);
                } else
                    ((float*)Cout)[(size_t)row*N + col] = v;
            }
        }
    }
}

// ---------------- flash attention, swapped-QK, 32x32 MFMA ----------------
// 128 q rows per block (4 waves x 32 q). KV tiles of 64, double-buffered
// global_load_lds staging with counted vmcnt(4). Q pre-scaled by
// log2(e)/sqrt(HD). Lane owns q-column l31; softmax fully in-register.
__global__ __launch_bounds__(256)
void attn_fwd4(const u16* __restrict__ Q, const u16* __restrict__ K,
               const u16* __restrict__ Vt, u16* __restrict__ O)
{
    __shared__ __align__(16) char smem[32768];   // buf0: [K 8K][V 8K]; buf1 at +16K
    const int tid = threadIdx.x, lane = tid&63, wave = tid>>6;
    const int l31 = lane&31, hl = lane>>5;

    // XCD-chunked remap: XCD c handles bh in [8c, 8c+8) (K/V L2 reuse)
    int dlin = blockIdx.y*16 + blockIdx.x;
    int xc = dlin&7, t = dlin>>3;
    int bh = xc*8 + (t>>4), qt = t&15;
    int b = bh>>4, h = bh&15;

    const int qrow = qt*128 + wave*32 + l31;
    const size_t qgoff = ((size_t)(b*2048 + qrow))*1024 + h*64;
    const u16* Kg = K  + ((size_t)(b*2048))*1024 + h*64;
    const u16* Vg = Vt + ((size_t)(b*1024 + h*64))*2048;

    s16x8 bq[4];
    #pragma unroll
    for (int ks=0;ks<4;++ks)
        bq[ks] = *(const s16x8*)(Q + qgoff + 16*ks + 8*hl);

    float m_run = -1e30f, l_run = 0.0f;
    f32x16 oa0 = {}, oa1 = {};

    // hoisted staging addresses: chunk c=i*256+tid -> row=32i+(tid>>3);
    // src col-chunk q = (tid&7)^(row&7) is i-independent.
    const int r0 = tid>>3;
    const int qc = (tid&7) ^ (r0&7);
    const u16* kbase = Kg + (size_t)r0*1024 + qc*8;
    const u16* vbase = Vg + (size_t)r0*2048 + qc*8;
    const int ldst = tid*16;

    auto stage = [&](int kt, int buf){
        char* Kb = smem + buf*16384;
        char* Vb = Kb + 8192;
        const size_t kk = (size_t)kt*65536;   // kt*64*1024 elems
        const int kv0 = kt*64;
        gl16(kbase + kk,           Kb + ldst);
        gl16(kbase + kk + 32768,   Kb + 4096 + ldst);
        gl16(vbase + kv0,          Vb + ldst);
        gl16(vbase + kv0 + 65536,  Vb + 4096 + ldst);
    };

    // precomputed swizzled ds_read byte offsets (shared by K and V tiles)
    int kofs[8];
    #pragma unroll
    for (int hk=0;hk<2;++hk)
        #pragma unroll
        for (int ks=0;ks<4;++ks)
            kofs[hk*4+ks] = swz(hk*32 + l31, 32*ks + 16*hl);

    stage(0, 0);
    int cur = 0;

    for (int kt=0; kt<32; ++kt){
        if (kt+1 < 32){
            stage(kt+1, cur^1);
            asm volatile("s_waitcnt vmcnt(4)" ::: "memory");
        } else {
            asm volatile("s_waitcnt vmcnt(0)" ::: "memory");
        }
        __builtin_amdgcn_s_barrier();

        char* Kb = smem + cur*16384;
        char* Vb = Kb + 8192;

        // S^T[kv][q] = K-frag x Q-frag
        f32x16 s0 = {}, s1 = {};
        __builtin_amdgcn_s_setprio(1);
        #pragma unroll
        for (int ks=0; ks<4; ++ks){
            s16x8 ak0 = *(const s16x8*)(Kb + kofs[ks]);
            s16x8 ak1 = *(const s16x8*)(Kb + kofs[4+ks]);
            s0 = __builtin_amdgcn_mfma_f32_32x32x16_bf16(ak0, bq[ks], s0, 0,0,0);
            s1 = __builtin_amdgcn_mfma_f32_32x32x16_bf16(ak1, bq[ks], s1, 0,0,0);
        }
        __builtin_amdgcn_s_setprio(0);

        // row max (tree) + partner
        float tm[8];
        #pragma unroll
        for (int i=0;i<8;++i) tm[i] = fmaxf(fmaxf(fmaxf(s0[i], s0[i+8]), s1[i]), s1[i+8]);
        float pm = fmaxf(fmaxf(fmaxf(tm[0],tm[1]),fmaxf(tm[2],tm[3])),
                         fmaxf(fmaxf(tm[4],tm[5]),fmaxf(tm[6],tm[7])));
        pm = fmaxf(pm, __shfl_xor(pm, 32));

        // defer-max: rescale only when the wave really needs it
        if (!__all(pm - m_run <= 8.0f)){
            float mn  = fmaxf(m_run, pm);
            float scl = __builtin_amdgcn_exp2f(m_run - mn);
            oa0 *= scl; oa1 *= scl;
            l_run *= scl;
            m_run = mn;
        }

        // P = exp2(S - m_run)
        #pragma unroll
        for (int r=0; r<16; ++r){
            s0[r] = __builtin_amdgcn_exp2f(s0[r] - m_run);
            s1[r] = __builtin_amdgcn_exp2f(s1[r] - m_run);
        }
        // row sum (tree) + partner
        float ts[8];
        #pragma unroll
        for (int i=0;i<8;++i) ts[i] = (s0[i]+s0[i+8]) + (s1[i]+s1[i+8]);
        float rs = ((ts[0]+ts[1])+(ts[2]+ts[3])) + ((ts[4]+ts[5])+(ts[6]+ts[7]));
        rs += __shfl_xor(rs, 32);
        l_run += rs;

        // pack P -> bf16 words, redistribute via permlane32_swap
        s16x8 bP[4];
        #pragma unroll
        for (int f=0; f<2; ++f){
            const f32x16& sf = f ? s1 : s0;
            u32 W[8];
            #pragma unroll
            for (int w=0; w<8; ++w) W[w] = cvtpk(sf[2*w], sf[2*w+1]);
            #pragma unroll
            for (int s=0; s<2; ++s){
                u32 x0 = W[4*s+0], y0 = W[4*s+2];
                u32 x1 = W[4*s+1], y1 = W[4*s+3];
                plswap(x0, y0);
                plswap(x1, y1);
                union { u32 w[4]; s16x8 v; } u;
                u.w[0]=x0; u.w[1]=x1; u.w[2]=y0; u.w[3]=y1;
                bP[2*f+s] = u.v;
            }
        }

        // O^T += V-frag x P^T
        __builtin_amdgcn_s_setprio(1);
        #pragma unroll
        for (int ks=0; ks<4; ++ks){
            s16x8 av0 = *(const s16x8*)(Vb + kofs[ks]);
            s16x8 av1 = *(const s16x8*)(Vb + kofs[4+ks]);
            oa0 = __builtin_amdgcn_mfma_f32_32x32x16_bf16(av0, bP[ks], oa0, 0,0,0);
            oa1 = __builtin_amdgcn_mfma_f32_32x32x16_bf16(av1, bP[ks], oa1, 0,0,0);
        }
        __builtin_amdgcn_s_setprio(0);

        __builtin_amdgcn_s_barrier();
        cur ^= 1;
    }

    // epilogue: O[q][d], d = fd*32 + 8*rq + 4*hl + e
    float inv = 1.0f / l_run;
    u16* Ob = O + qgoff;
    #pragma unroll
    for (int fd=0; fd<2; ++fd){
        const f32x16& oaf = fd ? oa1 : oa0;
        #pragma unroll
        for (int rq=0; rq<4; ++rq){
            s16x4 o;
            #pragma unroll
            for (int e=0;e<4;++e) o[e] = (short)f2bf(oaf[rq*4+e] * inv);
            *(s16x4*)(Ob + fd*32 + rq*8 + hl*4) = o;
        }
    }
}

extern "C" void kernel_launch(void* const* d_in, const int* in_sizes, int n_in,
                              void* d_out, int out_size, void* d_ws, size_t ws_size,
                              hipStream_t stream)
{
    const float* query = (const float*)d_in[0];
    const float* kvin  = (const float*)d_in[1];
    const float* Wq = (const float*)d_in[2];
    const float* bq = (const float*)d_in[3];
    const float* Wk = (const float*)d_in[4];
    const float* bk = (const float*)d_in[5];
    const float* Wv = (const float*)d_in[6];
    const float* bv = (const float*)d_in[7];
    const float* Wo = (const float*)d_in[8];
    const float* bo = (const float*)d_in[9];

    const int M = 8192, D = 1024;
    const size_t MB = 1024ull*1024ull;
    u16* Qb  = (u16*)d_ws;
    u16* Kb  = Qb  + 8*MB;
    u16* Vtb = Kb  + 8*MB;
    u16* Ob  = Vtb + 8*MB;          // 64 MB

    if (ws_size >= 66*MB) {
        u16* Wt   = Ob + 8*MB;      // ws[64MB..66MB)
        u16* qbf  = (u16*)d_out;    // d_out as scratch until final GEMM
        u16* kvbf = qbf + 8*MB;

        cvtbf<<<4096,256,0,stream>>>(query, qbf);
        cvtbf<<<4096,256,0,stream>>>(kvin,  kvbf);

        dim3 tg(16,16), gg(64,8);
        transW<<<tg,256,0,stream>>>(Wq, Wt);
        gemm128<0><<<gg,256,0,stream>>>(qbf,  Wt, bq, Qb,  M, D, D, QSCALE);
        transW<<<tg,256,0,stream>>>(Wk, Wt);
        gemm128<0><<<gg,256,0,stream>>>(kvbf, Wt, bk, Kb,  M, D, D, 1.0f);
        transW<<<tg,256,0,stream>>>(Wv, Wt);
        gemm128<2><<<gg,256,0,stream>>>(kvbf, Wt, bv, Vtb, M, D, D, 1.0f);

        attn_fwd4<<<dim3(16,64),256,0,stream>>>(Qb, Kb, Vtb, Ob);

        transW<<<tg,256,0,stream>>>(Wo, Wt);
        gemm128<3><<<gg,256,0,stream>>>(Ob, Wt, bo, d_out, M, D, D, 1.0f);
    } else {
        dim3 gg(128,16);
        gemm_bias_64<true ,0><<<gg,256,0,stream>>>(query, Wq, bq, Qb,  M, D, D, QSCALE);
        gemm_bias_64<true ,0><<<gg,256,0,stream>>>(kvin,  Wk, bk, Kb,  M, D, D, 1.0f);
        gemm_bias_64<true ,2><<<gg,256,0,stream>>>(kvin,  Wv, bv, Vtb, M, D, D, 1.0f);
        attn_fwd4<<<dim3(16,64),256,0,stream>>>(Qb, Kb, Vtb, Ob);
        gemm_bias_64<false,3><<<gg,256,0,stream>>>(Ob, Wo, bo, d_out, M, D, D, 1.0f);
    }
}

// Round 5
// 230.269 us; speedup vs baseline: 2.2624x; 1.0226x over previous
//
#include <hip/hip_runtime.h>

// CrossAttention B=4, S=2048, D=H=1024, NH=16, HD=64.
// R5: attn software-pipelined across KV tiles (QK(t+1) MFMA overlaps
//     softmax(t) VALU); launch fusion (fused cvt, fused 3-way transW).

typedef short s16x8 __attribute__((ext_vector_type(8)));
typedef short s16x4 __attribute__((ext_vector_type(4)));
typedef float f32x4 __attribute__((ext_vector_type(4)));
typedef float f32x16 __attribute__((ext_vector_type(16)));
typedef unsigned short u16;
typedef unsigned int u32;

__device__ __forceinline__ u16 f2bf(float f){
    union{float f;u32 u;} v; v.f=f;
    u32 r = v.u + 0x7fffu + ((v.u>>16)&1u);
    return (u16)(r>>16);
}
// 128B-row LDS tile; XOR swizzle on bits 4..6
__device__ __forceinline__ int swz(int row,int colB){ return row*128 + (colB ^ ((row&7)<<4)); }

__device__ __forceinline__ void gl16(const void* g, void* l){
    __builtin_amdgcn_global_load_lds((__attribute__((address_space(1))) void*)(void*)g,
                                     (__attribute__((address_space(3))) void*)l, 16, 0, 0);
}
__device__ __forceinline__ u32 cvtpk(float lo, float hi){
    u32 r; asm("v_cvt_pk_bf16_f32 %0, %1, %2" : "=v"(r) : "v"(lo), "v"(hi)); return r;
}
__device__ __forceinline__ void plswap(u32& a, u32& b){
    asm("v_permlane32_swap_b32 %0, %1" : "+v"(a), "+v"(b));
}

#define QSCALE 0.1803368801111204f  /* log2(e)/sqrt(64) */

// ---------------- fused fp32 -> bf16 (query then kv) ----------------
__global__ __launch_bounds__(256) void cvtbf2(const float* __restrict__ a, const float* __restrict__ b,
                                              u16* __restrict__ oa, u16* __restrict__ ob){
    int blk = blockIdx.x;
    const float* in = a; u16* out = oa;
    if (blk >= 4096){ in = b; out = ob; blk -= 4096; }
    size_t i = ((size_t)blk*256 + threadIdx.x)*8;
    f32x4 x = *(const f32x4*)(in+i), y = *(const f32x4*)(in+i+4);
    s16x8 o;
    #pragma unroll
    for (int j=0;j<4;++j){ o[j]=(short)f2bf(x[j]); o[4+j]=(short)f2bf(y[j]); }
    *(s16x8*)(out+i) = o;
}

// ---------------- W[1024][1024] fp32 -> Wt[n][k] bf16 ----------------
__device__ __forceinline__ void transW_body(const float* __restrict__ W, u16* __restrict__ Wt){
    __shared__ u16 T[64*68];
    const int tid = threadIdx.x;
    const int n0 = blockIdx.x*64, k0 = blockIdx.y*64;
    const int tr = tid>>4, tc = (tid&15)*4;
    #pragma unroll
    for (int p=0;p<4;++p){
        int k = p*16 + tr;
        f32x4 v = *(const f32x4*)(W + (size_t)(k0+k)*1024 + n0 + tc);
        s16x4 o;
        #pragma unroll
        for (int j=0;j<4;++j) o[j]=(short)f2bf(v[j]);
        *(s16x4*)(T + k*68 + tc) = o;
    }
    __syncthreads();
    #pragma unroll
    for (int p=0;p<4;++p){
        int n = p*16 + tr;
        s16x4 o;
        #pragma unroll
        for (int e=0;e<4;++e) o[e] = (short)T[(tc+e)*68 + n];
        *(s16x4*)(Wt + (size_t)(n0+n)*1024 + k0 + tc) = o;
    }
}
__global__ __launch_bounds__(256) void transW(const float* __restrict__ W, u16* __restrict__ Wt){
    transW_body(W, Wt);
}
__global__ __launch_bounds__(256) void transW3(const float* __restrict__ W0, const float* __restrict__ W1,
                                               const float* __restrict__ W2,
                                               u16* __restrict__ O0, u16* __restrict__ O1, u16* __restrict__ O2){
    const float* W = blockIdx.z==0 ? W0 : (blockIdx.z==1 ? W1 : W2);
    u16*       Wt = blockIdx.z==0 ? O0 : (blockIdx.z==1 ? O1 : O2);
    transW_body(W, Wt);
}

// ---------------- GEMM: C = A[M,K](bf16) @ Bt[N,K]^T(bf16) + bias ----------
// 128x128 tile, BK=64, double buffer with counted vmcnt(8).
// EPI: 0 bf16 out ; 2 bf16 V-transposed ; 3 f32 out
template<int EPI>
__global__ __launch_bounds__(256)
void gemm128(const u16* __restrict__ A, const u16* __restrict__ Bt,
             const float* __restrict__ bias, void* __restrict__ C,
             int M, int N, int K, float scale)
{
    __shared__ __align__(16) u16 As[2][128*64];
    __shared__ __align__(16) u16 Bs[2][128*64];
    const int tid = threadIdx.x, lane = tid&63, wave = tid>>6;
    const int ln = lane&15, g = lane>>4;
    const int wm = wave>>1, wn = wave&1;
    const int bm = blockIdx.x, bn = blockIdx.y;

    f32x4 acc[4][4] = {};

    const int r0g = tid>>3, cc8 = (tid&7)*8;
    const u16* aA = A  + (size_t)(bm*128 + r0g)*K + cc8;
    const u16* aB = Bt + (size_t)(bn*128 + r0g)*K + cc8;

    auto stage = [&](int k0, int buf){
        char* pa = (char*)As[buf] + tid*16;
        char* pb = (char*)Bs[buf] + tid*16;
        #pragma unroll
        for (int i=0;i<4;++i){
            gl16(aA + k0 + i*32*K, pa + i*4096);
            gl16(aB + k0 + i*32*K, pb + i*4096);
        }
    };

    stage(0, 0);
    int cur = 0;
    for (int k0=0; k0<K; k0+=64){
        if (k0+64 < K){
            stage(k0+64, cur^1);
            asm volatile("s_waitcnt vmcnt(8)" ::: "memory");
        } else {
            asm volatile("s_waitcnt vmcnt(0)" ::: "memory");
        }
        __builtin_amdgcn_s_barrier();
        #pragma unroll
        for (int kk=0;kk<2;++kk){
            s16x8 af[4], bf[4];
            #pragma unroll
            for (int mi=0;mi<4;++mi)
                af[mi] = *(const s16x8*)((const char*)As[cur] + (size_t)(wm*64+mi*16+ln)*128 + kk*64 + g*16);
            #pragma unroll
            for (int ni=0;ni<4;++ni)
                bf[ni] = *(const s16x8*)((const char*)Bs[cur] + (size_t)(wn*64+ni*16+ln)*128 + kk*64 + g*16);
            #pragma unroll
            for (int mi=0;mi<4;++mi)
                #pragma unroll
                for (int ni=0;ni<4;++ni)
                    acc[mi][ni] = __builtin_amdgcn_mfma_f32_16x16x32_bf16(af[mi], bf[ni], acc[mi][ni], 0,0,0);
        }
        __builtin_amdgcn_s_barrier();
        cur ^= 1;
    }

    #pragma unroll
    for (int mi=0;mi<4;++mi){
        #pragma unroll
        for (int ni=0;ni<4;++ni){
            int col = bn*128 + wn*64 + ni*16 + ln;
            float bv = bias[col];
            #pragma unroll
            for (int r=0;r<4;++r){
                int row = bm*128 + wm*64 + mi*16 + 4*g + r;
                float v = (acc[mi][ni][r] + bv) * scale;
                if constexpr (EPI==0)
                    ((u16*)C)[(size_t)row*N + col] = f2bf(v);
                else if constexpr (EPI==2){
                    int b = row>>11, s = row&2047;
                    ((u16*)C)[((size_t)(b*1024 + col))*2048 + s] = f2bf(v);
                } else
                    ((float*)C)[(size_t)row*N + col] = v;
            }
        }
    }
}

// ---------------- fallback GEMM (64x64, fp32-A capable) ----------------
template<bool A_IS_F32, int EPI>
__global__ __launch_bounds__(256)
void gemm_bias_64(const void* __restrict__ Av, const float* __restrict__ W,
                  const float* __restrict__ bias, void* __restrict__ Cout,
                  int M, int N, int K, float scale)
{
    __shared__ __align__(16) char smem[16384];
    char* As = smem;
    char* Ws = smem + 8192;
    const int tid  = threadIdx.x;
    const int lane = tid & 63, wave = tid >> 6;
    const int g = lane >> 4, ln = lane & 15;
    const int wm = wave >> 1, wn = wave & 1;
    const int bm = blockIdx.x, bn = blockIdx.y;
    f32x4 acc[2][2] = {};
    const int srow = tid >> 2;
    const int sch  = (tid & 3) * 16;

    for (int k0 = 0; k0 < K; k0 += 64) {
        if constexpr (A_IS_F32) {
            const float* a = (const float*)Av + (size_t)(bm*64+srow)*K + k0 + sch;
            const f32x4* a4 = (const f32x4*)a;
            #pragma unroll
            for (int c = 0; c < 2; ++c) {
                f32x4 x = a4[c*2+0], y = a4[c*2+1];
                s16x8 wv;
                #pragma unroll
                for (int j = 0; j < 4; ++j){ wv[j]=(short)f2bf(x[j]); wv[4+j]=(short)f2bf(y[j]); }
                *(s16x8*)(As + swz(srow, sch*2 + c*16)) = wv;
            }
        } else {
            const u16* a = (const u16*)Av + (size_t)(bm*64+srow)*K + k0 + sch;
            *(s16x8*)(As + swz(srow, sch*2 + 0))  = *(const s16x8*)(a + 0);
            *(s16x8*)(As + swz(srow, sch*2 + 16)) = *(const s16x8*)(a + 8);
        }
        {
            const float* wsrc = W + (size_t)(k0+srow)*N + bn*64 + sch;
            #pragma unroll
            for (int j = 0; j < 16; ++j) {
                int n = sch + j;
                *(short*)(Ws + n*128 + ((srow*2) ^ ((n&7)<<4))) = (short)f2bf(wsrc[j]);
            }
        }
        __syncthreads();
        #pragma unroll
        for (int kk = 0; kk < 2; ++kk) {
            s16x8 af[2], bfr[2];
            #pragma unroll
            for (int mi = 0; mi < 2; ++mi)
                af[mi] = *(const s16x8*)(As + swz(wm*32+mi*16+ln, kk*64 + g*16));
            #pragma unroll
            for (int ni = 0; ni < 2; ++ni)
                bfr[ni] = *(const s16x8*)(Ws + swz(wn*32+ni*16+ln, kk*64 + g*16));
            #pragma unroll
            for (int mi = 0; mi < 2; ++mi)
                #pragma unroll
                for (int ni = 0; ni < 2; ++ni)
                    acc[mi][ni] = __builtin_amdgcn_mfma_f32_16x16x32_bf16(af[mi], bfr[ni], acc[mi][ni], 0,0,0);
        }
        __syncthreads();
    }
    #pragma unroll
    for (int mi = 0; mi < 2; ++mi){
        #pragma unroll
        for (int ni = 0; ni < 2; ++ni){
            int col = bn*64 + wn*32 + ni*16 + ln;
            float bv = bias[col];
            #pragma unroll
            for (int r = 0; r < 4; ++r){
                int row = bm*64 + wm*32 + mi*16 + 4*g + r;
                float v = (acc[mi][ni][r] + bv) * scale;
                if constexpr (EPI==0)
                    ((u16*)Cout)[(size_t)row*N + col] = f2bf(v);
                else if constexpr (EPI==2){
                    int b = row>>11, s = row&2047;
                    ((u16*)Cout)[((size_t)(b*1024+col))*2048 + s] = f2bf(v);
                } else
                    ((float*)Cout)[(size_t)row*N + col] = v;
            }
        }
    }
}

// ---------------- flash attention, pipelined swapped-QK 32x32 --------------
// 128 q rows/block (4 waves x 32 q). Two S-tiles in flight: QK(t+1) MFMA is
// issued before softmax(t), so softmax VALU overlaps matrix-pipe work.
__global__ __launch_bounds__(256)
void attn_fwd5(const u16* __restrict__ Q, const u16* __restrict__ K,
               const u16* __restrict__ Vt, u16* __restrict__ O)
{
    __shared__ __align__(16) char smem[32768];   // slot: [K 8K][V 8K] x2
    const int tid = threadIdx.x, lane = tid&63, wave = tid>>6;
    const int l31 = lane&31, hl = lane>>5;

    // XCD-chunked remap: XCD c handles bh in [8c, 8c+8)
    int dlin = blockIdx.y*16 + blockIdx.x;
    int xc = dlin&7, t0 = dlin>>3;
    int bh = xc*8 + (t0>>4), qt = t0&15;
    int b = bh>>4, h = bh&15;

    const int qrow = qt*128 + wave*32 + l31;
    const size_t qgoff = ((size_t)(b*2048 + qrow))*1024 + h*64;
    const u16* Kg = K  + ((size_t)(b*2048))*1024 + h*64;
    const u16* Vg = Vt + ((size_t)(b*1024 + h*64))*2048;

    s16x8 bq[4];
    #pragma unroll
    for (int ks=0;ks<4;++ks)
        bq[ks] = *(const s16x8*)(Q + qgoff + 16*ks + 8*hl);

    float m_run = -1e30f, l_run = 0.0f;
    f32x16 oa0 = {}, oa1 = {};

    // hoisted staging addresses (chunk-xor is i-independent)
    const int r0 = tid>>3;
    const int qc = (tid&7) ^ (r0&7);
    const u16* kbase = Kg + (size_t)r0*1024 + qc*8;
    const u16* vbase = Vg + (size_t)r0*2048 + qc*8;
    const int ldst = tid*16;

    auto stage = [&](int kt, int buf){
        char* Kb = smem + buf*16384;
        char* Vb = Kb + 8192;
        const size_t kkOff = (size_t)kt*65536;
        const int kv0 = kt*64;
        gl16(kbase + kkOff,           Kb + ldst);
        gl16(kbase + kkOff + 32768,   Kb + 4096 + ldst);
        gl16(vbase + kv0,             Vb + ldst);
        gl16(vbase + kv0 + 65536,     Vb + 4096 + ldst);
    };

    int kofs[8];
    #pragma unroll
    for (int hk=0;hk<2;++hk)
        #pragma unroll
        for (int ks=0;ks<4;++ks)
            kofs[hk*4+ks] = swz(hk*32 + l31, 32*ks + 16*hl);

    auto qk = [&](int buf, f32x16& sA, f32x16& sB){
        char* Kb = smem + buf*16384;
        f32x16 a = {}, c = {};
        __builtin_amdgcn_s_setprio(1);
        #pragma unroll
        for (int ks=0; ks<4; ++ks){
            s16x8 ak0 = *(const s16x8*)(Kb + kofs[ks]);
            s16x8 ak1 = *(const s16x8*)(Kb + kofs[4+ks]);
            a = __builtin_amdgcn_mfma_f32_32x32x16_bf16(ak0, bq[ks], a, 0,0,0);
            c = __builtin_amdgcn_mfma_f32_32x32x16_bf16(ak1, bq[ks], c, 0,0,0);
        }
        __builtin_amdgcn_s_setprio(0);
        sA = a; sB = c;
    };

    // softmax + pack on (s0,s1) -> bP; updates m_run,l_run, rescales oa
    auto smpack = [&](f32x16& s0, f32x16& s1, s16x8* bP){
        float tm[8];
        #pragma unroll
        for (int i=0;i<8;++i) tm[i] = fmaxf(fmaxf(fmaxf(s0[i], s0[i+8]), s1[i]), s1[i+8]);
        float pm = fmaxf(fmaxf(fmaxf(tm[0],tm[1]),fmaxf(tm[2],tm[3])),
                         fmaxf(fmaxf(tm[4],tm[5]),fmaxf(tm[6],tm[7])));
        pm = fmaxf(pm, __shfl_xor(pm, 32));
        if (!__all(pm - m_run <= 8.0f)){
            float mn  = fmaxf(m_run, pm);
            float scl = __builtin_amdgcn_exp2f(m_run - mn);
            oa0 *= scl; oa1 *= scl;
            l_run *= scl;
            m_run = mn;
        }
        #pragma unroll
        for (int r=0; r<16; ++r){
            s0[r] = __builtin_amdgcn_exp2f(s0[r] - m_run);
            s1[r] = __builtin_amdgcn_exp2f(s1[r] - m_run);
        }
        float ts[8];
        #pragma unroll
        for (int i=0;i<8;++i) ts[i] = (s0[i]+s0[i+8]) + (s1[i]+s1[i+8]);
        float rs = ((ts[0]+ts[1])+(ts[2]+ts[3])) + ((ts[4]+ts[5])+(ts[6]+ts[7]));
        rs += __shfl_xor(rs, 32);
        l_run += rs;
        #pragma unroll
        for (int f=0; f<2; ++f){
            const f32x16& sf = f ? s1 : s0;
            u32 W[8];
            #pragma unroll
            for (int w=0; w<8; ++w) W[w] = cvtpk(sf[2*w], sf[2*w+1]);
            #pragma unroll
            for (int s=0; s<2; ++s){
                u32 x0 = W[4*s+0], y0 = W[4*s+2];
                u32 x1 = W[4*s+1], y1 = W[4*s+3];
                plswap(x0, y0);
                plswap(x1, y1);
                union { u32 w[4]; s16x8 v; } u;
                u.w[0]=x0; u.w[1]=x1; u.w[2]=y0; u.w[3]=y1;
                bP[2*f+s] = u.v;
            }
        }
    };

    auto pv = [&](int buf, const s16x8* bP){
        char* Vb = smem + buf*16384 + 8192;
        __builtin_amdgcn_s_setprio(1);
        #pragma unroll
        for (int ks=0; ks<4; ++ks){
            s16x8 av0 = *(const s16x8*)(Vb + kofs[ks]);
            s16x8 av1 = *(const s16x8*)(Vb + kofs[4+ks]);
            oa0 = __builtin_amdgcn_mfma_f32_32x32x16_bf16(av0, bP[ks], oa0, 0,0,0);
            oa1 = __builtin_amdgcn_mfma_f32_32x32x16_bf16(av1, bP[ks], oa1, 0,0,0);
        }
        __builtin_amdgcn_s_setprio(0);
    };

    int cur = 0;
    // per-iteration body for tile kt (sC holds S(kt)); computes S(kt+1) into sN
    auto body = [&](f32x16& sC0, f32x16& sC1, f32x16& sN0, f32x16& sN1, int kt){
        asm volatile("s_waitcnt vmcnt(2)" ::: "memory");   // V(kt), K(kt+1) landed
        __builtin_amdgcn_s_barrier();
        qk(cur^1, sN0, sN1);                               // MFMA on K(kt+1)
        s16x8 bP[4];
        smpack(sC0, sC1, bP);                              // VALU overlaps QK
        pv(cur, bP);                                       // MFMA on V(kt)
        __builtin_amdgcn_s_barrier();                      // slot cur reads done
        if (kt < 30) stage(kt+2, cur);
        cur ^= 1;
    };

    // prologue: tiles 0,1 staged; compute S(0)
    stage(0, 0);
    stage(1, 1);
    asm volatile("s_waitcnt vmcnt(6)" ::: "memory");       // K(0) landed
    __builtin_amdgcn_s_barrier();
    f32x16 sa, sb, sc, sd;
    qk(0, sa, sb);

    int kt = 0;
    #pragma unroll 1
    for (int it=0; it<15; ++it){
        body(sa, sb, sc, sd, kt); ++kt;
        body(sc, sd, sa, sb, kt); ++kt;
    }
    body(sa, sb, sc, sd, kt); ++kt;                        // kt=30; S(31) in sc,sd

    // tail: tile 31
    asm volatile("s_waitcnt vmcnt(0)" ::: "memory");
    __builtin_amdgcn_s_barrier();
    {
        s16x8 bP[4];
        smpack(sc, sd, bP);
        pv(cur, bP);
    }

    // epilogue: O[q][d], d = fd*32 + 8*rq + 4*hl + e
    float inv = 1.0f / l_run;
    u16* Ob = O + qgoff;
    #pragma unroll
    for (int fd=0; fd<2; ++fd){
        const f32x16& oaf = fd ? oa1 : oa0;
        #pragma unroll
        for (int rq=0; rq<4; ++rq){
            s16x4 o;
            #pragma unroll
            for (int e=0;e<4;++e) o[e] = (short)f2bf(oaf[rq*4+e] * inv);
            *(s16x4*)(Ob + fd*32 + rq*8 + hl*4) = o;
        }
    }
}

extern "C" void kernel_launch(void* const* d_in, const int* in_sizes, int n_in,
                              void* d_out, int out_size, void* d_ws, size_t ws_size,
                              hipStream_t stream)
{
    const float* query = (const float*)d_in[0];
    const float* kvin  = (const float*)d_in[1];
    const float* Wq = (const float*)d_in[2];
    const float* bq = (const float*)d_in[3];
    const float* Wk = (const float*)d_in[4];
    const float* bk = (const float*)d_in[5];
    const float* Wv = (const float*)d_in[6];
    const float* bv = (const float*)d_in[7];
    const float* Wo = (const float*)d_in[8];
    const float* bo = (const float*)d_in[9];

    const int M = 8192, D = 1024;
    const size_t MB = 1024ull*1024ull;
    u16* Qb  = (u16*)d_ws;
    u16* Kb  = Qb  + 8*MB;
    u16* Vtb = Kb  + 8*MB;
    u16* Ob  = Vtb + 8*MB;          // 64 MB

    if (ws_size >= 66*MB) {
        u16* Wt0  = Ob + 8*MB;      // ws[64MB..66MB): Wt_q, later Wt_o
        u16* Wt1  = Ob;             // inside Ob region (dead before attn writes it)
        u16* Wt2  = Ob + 1*MB;
        u16* qbf  = (u16*)d_out;    // d_out as scratch until final GEMM
        u16* kvbf = qbf + 8*MB;

        cvtbf2<<<8192,256,0,stream>>>(query, kvin, qbf, kvbf);

        dim3 tg3(16,16,3), tg(16,16), gg(64,8);
        transW3<<<tg3,256,0,stream>>>(Wq, Wk, Wv, Wt0, Wt1, Wt2);
        gemm128<0><<<gg,256,0,stream>>>(qbf,  Wt0, bq, Qb,  M, D, D, QSCALE);
        transW<<<tg,256,0,stream>>>(Wo, Wt0);
        gemm128<0><<<gg,256,0,stream>>>(kvbf, Wt1, bk, Kb,  M, D, D, 1.0f);
        gemm128<2><<<gg,256,0,stream>>>(kvbf, Wt2, bv, Vtb, M, D, D, 1.0f);

        attn_fwd5<<<dim3(16,64),256,0,stream>>>(Qb, Kb, Vtb, Ob);

        gemm128<3><<<gg,256,0,stream>>>(Ob, Wt0, bo, d_out, M, D, D, 1.0f);
    } else {
        dim3 gg(128,16);
        gemm_bias_64<true ,0><<<gg,256,0,stream>>>(query, Wq, bq, Qb,  M, D, D, QSCALE);
        gemm_bias_64<true ,0><<<gg,256,0,stream>>>(kvin,  Wk, bk, Kb,  M, D, D, 1.0f);
        gemm_bias_64<true ,2><<<gg,256,0,stream>>>(kvin,  Wv, bv, Vtb, M, D, D, 1.0f);
        attn_fwd5<<<dim3(16,64),256,0,stream>>>(Qb, Kb, Vtb, Ob);
        gemm_bias_64<false,3><<<gg,256,0,stream>>>(Ob, Wo, bo, d_out, M, D, D, 1.0f);
    }
}